// Round 1
// baseline (4517.023 us; speedup 1.0000x reference)
//
#include <hip/hip_runtime.h>
#include <hip/hip_bf16.h>
#include <math.h>

#define B_ 4
#define S_ 2048
#define D_ 1024
#define H_ 16
#define DH_ 64
#define MLP_ 4096
#define MROWS (B_ * S_)   // 8192

// ---------------- LayerNorm ----------------
__global__ __launch_bounds__(256) void ln_k(const float* __restrict__ x,
                                            const float* __restrict__ g,
                                            const float* __restrict__ b,
                                            float* __restrict__ y) {
    int row = blockIdx.x;
    int tid = threadIdx.x;
    const float* xr = x + (size_t)row * D_;
    float4 v = *(const float4*)(xr + tid * 4);
    float s = v.x + v.y + v.z + v.w;
    float ss = v.x * v.x + v.y * v.y + v.z * v.z + v.w * v.w;
    for (int off = 32; off > 0; off >>= 1) {
        s += __shfl_down(s, off, 64);
        ss += __shfl_down(ss, off, 64);
    }
    __shared__ float rs[4], rss[4];
    int lane = tid & 63, wid = tid >> 6;
    if (lane == 0) { rs[wid] = s; rss[wid] = ss; }
    __syncthreads();
    s = rs[0] + rs[1] + rs[2] + rs[3];
    ss = rss[0] + rss[1] + rss[2] + rss[3];
    float mu = s * (1.0f / D_);
    float var = ss * (1.0f / D_) - mu * mu;
    float inv = rsqrtf(var + 1e-6f);
    float4 gg = *(const float4*)(g + tid * 4);
    float4 bb = *(const float4*)(b + tid * 4);
    float4 o;
    o.x = (v.x - mu) * inv * gg.x + bb.x;
    o.y = (v.y - mu) * inv * gg.y + bb.y;
    o.z = (v.z - mu) * inv * gg.z + bb.z;
    o.w = (v.w - mu) * inv * gg.w + bb.w;
    *(float4*)(y + (size_t)row * D_ + tid * 4) = o;
}

// ---------------- GEMM: C[M,N] = A[M,K] @ W[K,N] (+epilogue) ----------------
// EPI: 0 = +bias; 1 = gelu(+bias); 2 = +bias +res; 3 = accumulate into C
#define BM 128
#define BN 128
#define BK 16

__device__ __forceinline__ float gelu_f(float v) {
    return 0.5f * v * (1.0f + erff(v * 0.70710678118654752f));
}

template <int EPI>
__global__ __launch_bounds__(256) void gemm_k(const float* __restrict__ A,
                                              const float* __restrict__ W,
                                              const float* __restrict__ bias,
                                              const float* __restrict__ res,
                                              float* __restrict__ C,
                                              int M, int N, int K,
                                              int lda, int ldw, int ldc) {
    __shared__ float As[BK][BM];
    __shared__ float Bs[BK][BN];
    int tid = threadIdx.x;
    int row0 = blockIdx.y * BM;
    int col0 = blockIdx.x * BN;
    int tx = tid & 15;          // 0..15 -> 8 cols each
    int ty = tid >> 4;          // 0..15 -> 8 rows each
    int arow = tid >> 1;        // 0..127
    int ak0 = (tid & 1) * 8;    // 0 or 8
    int bkr = tid >> 4;         // 0..15
    int bn0 = (tid & 15) * 8;   // 0..120

    float acc[8][8];
#pragma unroll
    for (int i = 0; i < 8; ++i)
#pragma unroll
        for (int j = 0; j < 8; ++j) acc[i][j] = 0.0f;

    for (int k0 = 0; k0 < K; k0 += BK) {
        const float* Ap = A + (size_t)(row0 + arow) * lda + k0 + ak0;
        float4 a0 = *(const float4*)Ap;
        float4 a1 = *(const float4*)(Ap + 4);
        As[ak0 + 0][arow] = a0.x;
        As[ak0 + 1][arow] = a0.y;
        As[ak0 + 2][arow] = a0.z;
        As[ak0 + 3][arow] = a0.w;
        As[ak0 + 4][arow] = a1.x;
        As[ak0 + 5][arow] = a1.y;
        As[ak0 + 6][arow] = a1.z;
        As[ak0 + 7][arow] = a1.w;
        const float* Wp = W + (size_t)(k0 + bkr) * ldw + col0 + bn0;
        *(float4*)&Bs[bkr][bn0] = *(const float4*)Wp;
        *(float4*)&Bs[bkr][bn0 + 4] = *(const float4*)(Wp + 4);
        __syncthreads();
#pragma unroll
        for (int kk = 0; kk < BK; ++kk) {
            float ar[8], br[8];
            *(float4*)&ar[0] = *(float4*)&As[kk][ty * 8];
            *(float4*)&ar[4] = *(float4*)&As[kk][ty * 8 + 4];
            *(float4*)&br[0] = *(float4*)&Bs[kk][tx * 8];
            *(float4*)&br[4] = *(float4*)&Bs[kk][tx * 8 + 4];
#pragma unroll
            for (int i = 0; i < 8; ++i)
#pragma unroll
                for (int j = 0; j < 8; ++j) acc[i][j] += ar[i] * br[j];
        }
        __syncthreads();
    }

#pragma unroll
    for (int i = 0; i < 8; ++i) {
        int r = row0 + ty * 8 + i;
        float* Cp = C + (size_t)r * ldc + col0 + tx * 8;
#pragma unroll
        for (int j = 0; j < 8; j += 4) {
            float4 v;
            v.x = acc[i][j];
            v.y = acc[i][j + 1];
            v.z = acc[i][j + 2];
            v.w = acc[i][j + 3];
            if (EPI != 3) {
                const float* bp = bias + col0 + tx * 8 + j;
                float4 bb = *(const float4*)bp;
                v.x += bb.x; v.y += bb.y; v.z += bb.z; v.w += bb.w;
            }
            if (EPI == 1) {
                v.x = gelu_f(v.x); v.y = gelu_f(v.y);
                v.z = gelu_f(v.z); v.w = gelu_f(v.w);
            }
            if (EPI == 2) {
                float4 rr = *(const float4*)(res + (size_t)r * ldc + col0 + tx * 8 + j);
                v.x += rr.x; v.y += rr.y; v.z += rr.z; v.w += rr.w;
            }
            if (EPI == 3) {
                float4 old = *(const float4*)(Cp + j);
                v.x += old.x; v.y += old.y; v.z += old.z; v.w += old.w;
            }
            *(float4*)(Cp + j) = v;
        }
    }
}

// ---------------- Flash attention (fp32) ----------------
// grid: (S/64, B*H), block 256. 64 queries/block, 4 lanes per query (16 dims each).
__global__ __launch_bounds__(256) void attn_k(const float* __restrict__ Q,
                                              const float* __restrict__ K,
                                              const float* __restrict__ V,
                                              float* __restrict__ O) {
    int bh = blockIdx.y;
    int b = bh >> 4;
    int h = bh & 15;
    int q0 = blockIdx.x * 64;
    int tid = threadIdx.x;
    int wave = tid >> 6, lane = tid & 63;
    int ql = wave * 16 + (lane >> 2);   // 0..63
    int j = lane & 3;                   // dim-group
    size_t base = ((size_t)b * S_) * D_ + h * DH_;
    int q = q0 + ql;

    float qr[16];
    const float* Qp = Q + base + (size_t)q * D_ + j * 16;
#pragma unroll
    for (int d = 0; d < 16; d += 4) *(float4*)&qr[d] = *(const float4*)(Qp + d);

    float acc[16];
#pragma unroll
    for (int d = 0; d < 16; ++d) acc[d] = 0.0f;
    float m = -1e30f, l = 0.0f;

    __shared__ float Kt[64][64];
    __shared__ float Vt[64][64];

    for (int k0 = 0; k0 < S_; k0 += 64) {
        int r = tid >> 4;
        int c4 = (tid & 15) * 4;
#pragma unroll
        for (int rr = 0; rr < 64; rr += 16) {
            const float* kp = K + base + (size_t)(k0 + r + rr) * D_ + c4;
            *(float4*)&Kt[r + rr][c4] = *(const float4*)kp;
            const float* vp = V + base + (size_t)(k0 + r + rr) * D_ + c4;
            *(float4*)&Vt[r + rr][c4] = *(const float4*)vp;
        }
        __syncthreads();
#pragma unroll 1
        for (int c = 0; c < 2; ++c) {
            float sc[32];
            float cmax = -1e30f;
#pragma unroll
            for (int kk = 0; kk < 32; ++kk) {
                const float* kr = &Kt[c * 32 + kk][j * 16];
                float s = 0.0f;
#pragma unroll
                for (int d = 0; d < 16; ++d) s += qr[d] * kr[d];
                s += __shfl_xor(s, 1, 64);
                s += __shfl_xor(s, 2, 64);
                s *= 0.125f;
                sc[kk] = s;
                cmax = fmaxf(cmax, s);
            }
            float mnew = fmaxf(m, cmax);
            float f = __expf(m - mnew);
            l *= f;
#pragma unroll
            for (int d = 0; d < 16; ++d) acc[d] *= f;
#pragma unroll
            for (int kk = 0; kk < 32; ++kk) {
                float p = __expf(sc[kk] - mnew);
                l += p;
                const float* vr = &Vt[c * 32 + kk][j * 16];
#pragma unroll
                for (int d = 0; d < 16; ++d) acc[d] += p * vr[d];
            }
            m = mnew;
        }
        __syncthreads();
    }
    float invl = 1.0f / l;
    float* op = O + base + (size_t)q * D_ + j * 16;
#pragma unroll
    for (int d = 0; d < 16; d += 4) {
        float4 o;
        o.x = acc[d] * invl;
        o.y = acc[d + 1] * invl;
        o.z = acc[d + 2] * invl;
        o.w = acc[d + 3] * invl;
        *(float4*)(op + d) = o;
    }
}

// ---------------- launch ----------------
extern "C" void kernel_launch(void* const* d_in, const int* in_sizes, int n_in,
                              void* d_out, int out_size, void* d_ws, size_t ws_size,
                              hipStream_t stream) {
    const float* x     = (const float*)d_in[0];
    const float* Wq    = (const float*)d_in[1];
    const float* bq    = (const float*)d_in[2];
    const float* Wk    = (const float*)d_in[3];
    const float* bk    = (const float*)d_in[4];
    const float* Wv    = (const float*)d_in[5];
    const float* bv    = (const float*)d_in[6];
    const float* Wo    = (const float*)d_in[7];
    const float* bo    = (const float*)d_in[8];
    const float* ln1_g = (const float*)d_in[9];
    const float* ln1_b = (const float*)d_in[10];
    const float* ln2_g = (const float*)d_in[11];
    const float* ln2_b = (const float*)d_in[12];
    const float* W1    = (const float*)d_in[13];
    const float* b1    = (const float*)d_in[14];
    const float* W2    = (const float*)d_in[15];
    const float* b2    = (const float*)d_in[16];
    float* out = (float*)d_out;

    float* buf0 = (float*)d_ws;                       // xn, then attn out r
    float* buf1 = buf0 + (size_t)MROWS * D_;          // Q, then x2
    float* buf2 = buf1 + (size_t)MROWS * D_;          // K, then xn2
    float* buf3 = buf2 + (size_t)MROWS * D_;          // V, then mid chunk

    dim3 g8(D_ / BN, MROWS / BM);   // (8, 64)

    // 1. LN1
    ln_k<<<MROWS, 256, 0, stream>>>(x, ln1_g, ln1_b, buf0);
    // 2. Q,K,V
    gemm_k<0><<<g8, 256, 0, stream>>>(buf0, Wq, bq, nullptr, buf1, MROWS, D_, D_, D_, D_, D_);
    gemm_k<0><<<g8, 256, 0, stream>>>(buf0, Wk, bk, nullptr, buf2, MROWS, D_, D_, D_, D_, D_);
    gemm_k<0><<<g8, 256, 0, stream>>>(buf0, Wv, bv, nullptr, buf3, MROWS, D_, D_, D_, D_, D_);
    // 3. attention -> buf0
    dim3 ga(S_ / 64, B_ * H_);
    attn_k<<<ga, 256, 0, stream>>>(buf1, buf2, buf3, buf0);
    // 4. out proj + residual(x) -> buf1 (x2)
    gemm_k<2><<<g8, 256, 0, stream>>>(buf0, Wo, bo, x, buf1, MROWS, D_, D_, D_, D_, D_);
    // 5. LN2 -> buf2
    ln_k<<<MROWS, 256, 0, stream>>>(buf1, ln2_g, ln2_b, buf2);
    // 6. MLP in 4 column chunks of 1024
    for (int c = 0; c < 4; ++c) {
        gemm_k<1><<<g8, 256, 0, stream>>>(buf2, W1 + c * 1024, b1 + c * 1024, nullptr,
                                          buf3, MROWS, 1024, D_, D_, MLP_, 1024);
        if (c == 0) {
            gemm_k<2><<<g8, 256, 0, stream>>>(buf3, W2 + (size_t)c * 1024 * D_, b2, buf1,
                                              out, MROWS, D_, 1024, 1024, D_, D_);
        } else {
            gemm_k<3><<<g8, 256, 0, stream>>>(buf3, W2 + (size_t)c * 1024 * D_, nullptr, nullptr,
                                              out, MROWS, D_, 1024, 1024, D_, D_);
        }
    }
}

// Round 2
// 619.218 us; speedup vs baseline: 7.2947x; 7.2947x over previous
//
#include <hip/hip_runtime.h>
#include <math.h>

#define B_ 4
#define S_ 2048
#define D_ 1024
#define H_ 16
#define MLP_ 4096
#define MROWS 8192

typedef __attribute__((ext_vector_type(4))) float f32x4;
typedef __attribute__((ext_vector_type(8))) __bf16 bf16x8;
typedef __attribute__((ext_vector_type(4))) unsigned short us4;
typedef __attribute__((ext_vector_type(8))) unsigned short us8;
typedef unsigned short u16;
typedef unsigned int u32;

__device__ __forceinline__ u16 f2bf(float f) {
    union { float f; u32 u; } v; v.f = f;
    u32 r = v.u + 0x7FFFu + ((v.u >> 16) & 1u);
    return (u16)(r >> 16);
}

__device__ __forceinline__ void gload16(const void* g, void* l) {
    __builtin_amdgcn_global_load_lds((const __attribute__((address_space(1))) u32*)g,
                                     (__attribute__((address_space(3))) u32*)l, 16, 0, 0);
}

__device__ __forceinline__ float gelu_f(float v) {
    return 0.5f * v * (1.0f + erff(v * 0.70710678118654752f));
}

// ---------------- LayerNorm: f32 in -> bf16 out ----------------
__global__ __launch_bounds__(256) void ln_bf16_k(const float* __restrict__ x,
                                                 const float* __restrict__ g,
                                                 const float* __restrict__ b,
                                                 u16* __restrict__ y) {
    int row = blockIdx.x;
    int tid = threadIdx.x;
    const float* xr = x + (size_t)row * D_;
    f32x4 v = *(const f32x4*)(xr + tid * 4);
    float s = v.x + v.y + v.z + v.w;
    float ss = v.x * v.x + v.y * v.y + v.z * v.z + v.w * v.w;
    for (int off = 32; off > 0; off >>= 1) {
        s += __shfl_down(s, off, 64);
        ss += __shfl_down(ss, off, 64);
    }
    __shared__ float rs[4], rss[4];
    int lane = tid & 63, wid = tid >> 6;
    if (lane == 0) { rs[wid] = s; rss[wid] = ss; }
    __syncthreads();
    s = rs[0] + rs[1] + rs[2] + rs[3];
    ss = rss[0] + rss[1] + rss[2] + rss[3];
    float mu = s * (1.0f / D_);
    float var = ss * (1.0f / D_) - mu * mu;
    float inv = rsqrtf(var + 1e-6f);
    f32x4 gg = *(const f32x4*)(g + tid * 4);
    f32x4 bb = *(const f32x4*)(b + tid * 4);
    us4 o;
    o.x = f2bf((v.x - mu) * inv * gg.x + bb.x);
    o.y = f2bf((v.y - mu) * inv * gg.y + bb.y);
    o.z = f2bf((v.z - mu) * inv * gg.z + bb.z);
    o.w = f2bf((v.w - mu) * inv * gg.w + bb.w);
    *(us4*)(y + (size_t)row * D_ + tid * 4) = o;
}

// ---------------- weight transpose+convert: W[K,N] f32 -> Wt[N,K] bf16 ----------------
__global__ __launch_bounds__(256) void wtrans_k(const float* __restrict__ W,
                                                u16* __restrict__ Wt, int K, int N) {
    __shared__ float T[32][33];
    int tid = threadIdx.x;
    int k0 = blockIdx.y * 32, n0 = blockIdx.x * 32;
    int r = tid >> 3, c4 = (tid & 7) * 4;
    f32x4 v = *(const f32x4*)&W[(size_t)(k0 + r) * N + n0 + c4];
    T[r][c4 + 0] = v.x; T[r][c4 + 1] = v.y; T[r][c4 + 2] = v.z; T[r][c4 + 3] = v.w;
    __syncthreads();
    int n = tid >> 3, kk = (tid & 7) * 4;
    us4 o;
    o.x = f2bf(T[kk + 0][n]);
    o.y = f2bf(T[kk + 1][n]);
    o.z = f2bf(T[kk + 2][n]);
    o.w = f2bf(T[kk + 3][n]);
    *(us4*)&Wt[(size_t)(n0 + n) * K + k0 + kk] = o;
}

// ---------------- V transpose: V bf16 [B*S,D] -> Vt bf16 [B*H*64][S] ----------------
__global__ __launch_bounds__(256) void vtrans_k(const u16* __restrict__ V,
                                                u16* __restrict__ Vt) {
    __shared__ u16 T[64][80];
    int tid = threadIdx.x;
    int s0 = blockIdx.x * 64;
    int bh = blockIdx.y, b = bh >> 4, h = bh & 15;
    int r = tid >> 2, c0 = (tid & 3) * 16;
    const u16* src = V + (size_t)(b * S_ + s0 + r) * D_ + h * 64 + c0;
    us8 v0 = *(const us8*)src;
    us8 v1 = *(const us8*)(src + 8);
    *(us8*)&T[r][c0] = v0;
    *(us8*)&T[r][c0 + 8] = v1;
    __syncthreads();
    int dh = tid >> 2, s8 = (tid & 3) * 16;
    us8 o0, o1;
#pragma unroll
    for (int i = 0; i < 8; ++i) { o0[i] = T[s8 + i][dh]; o1[i] = T[s8 + 8 + i][dh]; }
    u16* dst = Vt + (size_t)(bh * 64 + dh) * S_ + s0 + s8;
    *(us8*)dst = o0;
    *(us8*)(dst + 8) = o1;
}

// ---------------- bf16 MFMA GEMM: C[M,N] = A[M,K] @ Wt[N,K]^T (+epilogue) ----------------
// EPI: 0 = +bias -> bf16 ; 1 = gelu(+bias) -> bf16 ; 2 = +bias +res -> f32
template <int EPI>
__global__ __launch_bounds__(256) void gemm_bf16(const u16* __restrict__ A,
                                                 const u16* __restrict__ Wt,
                                                 const float* __restrict__ bias,
                                                 const float* __restrict__ res,
                                                 void* __restrict__ Cout,
                                                 int M, int N, int K) {
    __shared__ u16 As[128 * 32];
    __shared__ u16 Bs[128 * 32];
    const int tid = threadIdx.x;
    const int lane = tid & 63;
    const int w = tid >> 6;
    const int row0 = blockIdx.y * 128;
    const int col0 = blockIdx.x * 128;
    const int l15 = lane & 15, l16 = lane >> 4;
    const int wr = w >> 1, wc = w & 1;

    f32x4 acc[4][4];
#pragma unroll
    for (int i = 0; i < 4; ++i)
#pragma unroll
        for (int j = 0; j < 4; ++j) acc[i][j] = (f32x4){0.f, 0.f, 0.f, 0.f};

    const int srow = w * 32 + (lane >> 2);
    const size_t sboff = (size_t)(lane & 3) * 16;
    const char* Ag = (const char*)A + ((size_t)(row0 + srow) * K) * 2 + sboff;
    const char* Bg = (const char*)Wt + ((size_t)(col0 + srow) * K) * 2 + sboff;
    const size_t rstep = (size_t)16 * K * 2;
    char* AsW = (char*)As + (w * 32) * 64;
    char* BsW = (char*)Bs + (w * 32) * 64;

    for (int k0 = 0; k0 < K; k0 += 32) {
        size_t kb = (size_t)k0 * 2;
        gload16(Ag + kb, AsW);
        gload16(Ag + kb + rstep, AsW + 1024);
        gload16(Bg + kb, BsW);
        gload16(Bg + kb + rstep, BsW + 1024);
        __syncthreads();
        bf16x8 af[4], bfr[4];
#pragma unroll
        for (int f = 0; f < 4; ++f) {
            af[f] = *(const bf16x8*)((const char*)As + (size_t)(wr * 64 + f * 16 + l15) * 64 + (l16 << 4));
            bfr[f] = *(const bf16x8*)((const char*)Bs + (size_t)(wc * 64 + f * 16 + l15) * 64 + (l16 << 4));
        }
#pragma unroll
        for (int fi = 0; fi < 4; ++fi)
#pragma unroll
            for (int fj = 0; fj < 4; ++fj)
                acc[fi][fj] = __builtin_amdgcn_mfma_f32_16x16x32_bf16(af[fi], bfr[fj], acc[fi][fj], 0, 0, 0);
        __syncthreads();
    }

    const int rb = row0 + wr * 64 + (l16 << 2);
    const int cb = col0 + wc * 64 + l15;
#pragma unroll
    for (int fi = 0; fi < 4; ++fi)
#pragma unroll
        for (int fj = 0; fj < 4; ++fj) {
            int c = cb + fj * 16;
            float bv = bias[c];
#pragma unroll
            for (int rr = 0; rr < 4; ++rr) {
                int r = rb + fi * 16 + rr;
                float v = acc[fi][fj][rr] + bv;
                if (EPI == 1) v = gelu_f(v);
                if (EPI == 2) {
                    v += res[(size_t)r * N + c];
                    ((float*)Cout)[(size_t)r * N + c] = v;
                } else {
                    ((u16*)Cout)[(size_t)r * N + c] = f2bf(v);
                }
            }
        }
}

// ---------------- MFMA flash attention ----------------
// grid (S/64, B*H), block 256 (4 waves, 16 query-rows each).
__global__ __launch_bounds__(256) void attn_mfma(const u16* __restrict__ Q,
                                                 const u16* __restrict__ K,
                                                 const u16* __restrict__ Vt,
                                                 u16* __restrict__ O) {
    __shared__ u16 Ks[64 * 64];
    __shared__ u16 Vs[64 * 64];
    __shared__ u16 Ps[4][16 * 64];
    const int tid = threadIdx.x, lane = tid & 63, w = tid >> 6;
    const int bh = blockIdx.y, b = bh >> 4, h = bh & 15;
    const int q0 = blockIdx.x * 64;
    const int l15 = lane & 15, l16 = lane >> 4;

    const u16* Qp = Q + (size_t)(b * S_ + q0 + w * 16 + l15) * D_ + h * 64 + (l16 << 3);
    bf16x8 qf0 = *(const bf16x8*)Qp;
    bf16x8 qf1 = *(const bf16x8*)(Qp + 32);

    f32x4 oacc[4];
#pragma unroll
    for (int i = 0; i < 4; ++i) oacc[i] = (f32x4){0.f, 0.f, 0.f, 0.f};
    float mold[4] = {-1e30f, -1e30f, -1e30f, -1e30f};
    float lsum[4] = {0.f, 0.f, 0.f, 0.f};

    const int sr = lane >> 3;
    const size_t soff = (size_t)(((lane & 7) ^ sr) << 4);  // pre-swizzled source offset
    const char* Kg = (const char*)K + (size_t)b * S_ * D_ * 2 + (size_t)h * 128;
    const char* Vg = (const char*)Vt + (size_t)bh * 64 * S_ * 2;
    char* Pw = (char*)Ps[w];

    for (int kt = 0; kt < S_ / 64; ++kt) {
#pragma unroll
        for (int i = 0; i < 2; ++i) {
            int rbase = w * 16 + i * 8;
            gload16(Kg + (size_t)(kt * 64 + rbase + sr) * (D_ * 2) + soff, (char*)Ks + rbase * 128);
            gload16(Vg + (size_t)(rbase + sr) * (S_ * 2) + (size_t)kt * 128 + soff, (char*)Vs + rbase * 128);
        }
        __syncthreads();

        // S = Q @ K^T  (per wave: 16 q-rows x 64 keys)
        f32x4 sfr[4];
#pragma unroll
        for (int cf = 0; cf < 4; ++cf) {
            int r = cf * 16 + l15;
            int x0 = (l16 << 4) ^ ((r & 7) << 4);
            bf16x8 k0v = *(const bf16x8*)((const char*)Ks + r * 128 + x0);
            bf16x8 k1v = *(const bf16x8*)((const char*)Ks + r * 128 + (x0 ^ 64));
            f32x4 t = (f32x4){0.f, 0.f, 0.f, 0.f};
            t = __builtin_amdgcn_mfma_f32_16x16x32_bf16(qf0, k0v, t, 0, 0, 0);
            t = __builtin_amdgcn_mfma_f32_16x16x32_bf16(qf1, k1v, t, 0, 0, 0);
            sfr[cf] = t;
        }

        // online softmax (rows = (l16*4+rr), cols spread over 16 lanes x 4 frags)
        float p[4][4];
#pragma unroll
        for (int rr = 0; rr < 4; ++rr) {
            float s0 = sfr[0][rr] * 0.125f, s1 = sfr[1][rr] * 0.125f;
            float s2 = sfr[2][rr] * 0.125f, s3 = sfr[3][rr] * 0.125f;
            float mx = fmaxf(fmaxf(s0, s1), fmaxf(s2, s3));
#pragma unroll
            for (int d = 1; d < 16; d <<= 1) mx = fmaxf(mx, __shfl_xor(mx, d, 64));
            float mnew = fmaxf(mold[rr], mx);
            float al = __expf(mold[rr] - mnew);
            float p0 = __expf(s0 - mnew), p1 = __expf(s1 - mnew);
            float p2 = __expf(s2 - mnew), p3 = __expf(s3 - mnew);
            p[0][rr] = p0; p[1][rr] = p1; p[2][rr] = p2; p[3][rr] = p3;
            float rsv = p0 + p1 + p2 + p3;
#pragma unroll
            for (int d = 1; d < 16; d <<= 1) rsv += __shfl_xor(rsv, d, 64);
            lsum[rr] = lsum[rr] * al + rsv;
            mold[rr] = mnew;
#pragma unroll
            for (int fj = 0; fj < 4; ++fj) oacc[fj][rr] *= al;
        }

        // P -> LDS (bf16, swizzled; per-wave buffer, in-wave dependency only)
#pragma unroll
        for (int cf = 0; cf < 4; ++cf)
#pragma unroll
            for (int rr = 0; rr < 4; ++rr) {
                int prow = (l16 << 2) + rr;
                int pb = ((cf * 16 + l15) * 2) ^ ((prow & 7) << 4);
                *(u16*)(Pw + prow * 128 + pb) = f2bf(p[cf][rr]);
            }

        // O += P @ V
        {
            int prow = l15;
            int x0 = (l16 << 4) ^ ((prow & 7) << 4);
            bf16x8 pf0 = *(const bf16x8*)(Pw + prow * 128 + x0);
            bf16x8 pf1 = *(const bf16x8*)(Pw + prow * 128 + (x0 ^ 64));
#pragma unroll
            for (int fj = 0; fj < 4; ++fj) {
                int vr = fj * 16 + l15;
                int y0 = (l16 << 4) ^ ((vr & 7) << 4);
                bf16x8 v0 = *(const bf16x8*)((const char*)Vs + vr * 128 + y0);
                bf16x8 v1 = *(const bf16x8*)((const char*)Vs + vr * 128 + (y0 ^ 64));
                oacc[fj] = __builtin_amdgcn_mfma_f32_16x16x32_bf16(pf0, v0, oacc[fj], 0, 0, 0);
                oacc[fj] = __builtin_amdgcn_mfma_f32_16x16x32_bf16(pf1, v1, oacc[fj], 0, 0, 0);
            }
        }
        __syncthreads();
    }

    float inv[4];
#pragma unroll
    for (int rr = 0; rr < 4; ++rr) inv[rr] = 1.0f / lsum[rr];
#pragma unroll
    for (int fj = 0; fj < 4; ++fj)
#pragma unroll
        for (int rr = 0; rr < 4; ++rr) {
            int r = b * S_ + q0 + w * 16 + (l16 << 2) + rr;
            O[(size_t)r * D_ + h * 64 + fj * 16 + l15] = f2bf(oacc[fj][rr] * inv[rr]);
        }
}

// ---------------- launch ----------------
extern "C" void kernel_launch(void* const* d_in, const int* in_sizes, int n_in,
                              void* d_out, int out_size, void* d_ws, size_t ws_size,
                              hipStream_t stream) {
    const float* x     = (const float*)d_in[0];
    const float* Wq    = (const float*)d_in[1];
    const float* bq    = (const float*)d_in[2];
    const float* Wk    = (const float*)d_in[3];
    const float* bk    = (const float*)d_in[4];
    const float* Wv    = (const float*)d_in[5];
    const float* bv    = (const float*)d_in[6];
    const float* Wo    = (const float*)d_in[7];
    const float* bo    = (const float*)d_in[8];
    const float* ln1_g = (const float*)d_in[9];
    const float* ln1_b = (const float*)d_in[10];
    const float* ln2_g = (const float*)d_in[11];
    const float* ln2_b = (const float*)d_in[12];
    const float* W1    = (const float*)d_in[13];
    const float* b1    = (const float*)d_in[14];
    const float* W2    = (const float*)d_in[15];
    const float* b2    = (const float*)d_in[16];
    float* out = (float*)d_out;

    const size_t MB = 1ull << 20;
    char* ws = (char*)d_ws;
    u16* Qb   = (u16*)(ws + 0 * MB);      // 16MB [8192][1024]
    u16* Kb   = (u16*)(ws + 16 * MB);     // 16MB
    u16* Vb   = (u16*)(ws + 32 * MB);     // 16MB
    u16* aout = (u16*)(ws + 48 * MB);     // 16MB
    u16* mid  = (u16*)(ws + 0 * MB);      // 64MB [8192][4096] (reuses Q/K/V/aout)
    float* x2 = (float*)(ws + 64 * MB);   // 32MB f32
    u16* xn   = (u16*)(ws + 96 * MB);     // 16MB
    u16* Vt   = (u16*)(ws + 96 * MB);     // 16MB (reuses xn after QKV)
    u16* xn2  = (u16*)(ws + 96 * MB);     // 16MB (reuses Vt after attn)
    u16* Wqt  = (u16*)(ws + 112 * MB);    // 2MB each
    u16* Wkt  = Wqt + (size_t)D_ * D_;
    u16* Wvt  = Wkt + (size_t)D_ * D_;
    u16* Wot  = Wvt + (size_t)D_ * D_;
    u16* W1t  = (u16*)(ws + 112 * MB);    // 8MB (reuses Wq..Wo after out-proj)
    u16* W2t  = (u16*)(ws + 120 * MB);    // 8MB

    // weight conversions (W2t upfront; W1t deferred until Wq..Wo dead)
    wtrans_k<<<dim3(32, 32), 256, 0, stream>>>(Wq, Wqt, D_, D_);
    wtrans_k<<<dim3(32, 32), 256, 0, stream>>>(Wk, Wkt, D_, D_);
    wtrans_k<<<dim3(32, 32), 256, 0, stream>>>(Wv, Wvt, D_, D_);
    wtrans_k<<<dim3(32, 32), 256, 0, stream>>>(Wo, Wot, D_, D_);
    wtrans_k<<<dim3(32, 128), 256, 0, stream>>>(W2, W2t, MLP_, D_);

    // LN1
    ln_bf16_k<<<MROWS, 256, 0, stream>>>(x, ln1_g, ln1_b, xn);
    // QKV projections
    gemm_bf16<0><<<dim3(8, 64), 256, 0, stream>>>(xn, Wqt, bq, nullptr, Qb, MROWS, D_, D_);
    gemm_bf16<0><<<dim3(8, 64), 256, 0, stream>>>(xn, Wkt, bk, nullptr, Kb, MROWS, D_, D_);
    gemm_bf16<0><<<dim3(8, 64), 256, 0, stream>>>(xn, Wvt, bv, nullptr, Vb, MROWS, D_, D_);
    // V transpose per head
    vtrans_k<<<dim3(32, 64), 256, 0, stream>>>(Vb, Vt);
    // attention
    attn_mfma<<<dim3(32, 64), 256, 0, stream>>>(Qb, Kb, Vt, aout);
    // out projection + residual -> x2 (f32)
    gemm_bf16<2><<<dim3(8, 64), 256, 0, stream>>>(aout, Wot, bo, x, x2, MROWS, D_, D_);
    // W1 transpose (now safe), LN2
    wtrans_k<<<dim3(128, 32), 256, 0, stream>>>(W1, W1t, D_, MLP_);
    ln_bf16_k<<<MROWS, 256, 0, stream>>>(x2, ln2_g, ln2_b, xn2);
    // MLP
    gemm_bf16<1><<<dim3(32, 64), 256, 0, stream>>>(xn2, W1t, b1, nullptr, mid, MROWS, MLP_, D_);
    gemm_bf16<2><<<dim3(8, 64), 256, 0, stream>>>(mid, W2t, b2, x2, (void*)out, MROWS, D_, MLP_);
}

// Round 3
// 590.850 us; speedup vs baseline: 7.6450x; 1.0480x over previous
//
#include <hip/hip_runtime.h>
#include <math.h>

#define B_ 4
#define S_ 2048
#define D_ 1024
#define H_ 16
#define MLP_ 4096
#define MROWS 8192

typedef __attribute__((ext_vector_type(4))) float f32x4;
typedef __attribute__((ext_vector_type(8))) __bf16 bf16x8;
typedef __attribute__((ext_vector_type(4))) __bf16 bf16x4;
typedef __attribute__((ext_vector_type(8))) unsigned short us8;
typedef unsigned short u16;
typedef unsigned int u32;

__device__ __forceinline__ void gload16(const void* g, void* l) {
    __builtin_amdgcn_global_load_lds((const __attribute__((address_space(1))) u32*)g,
                                     (__attribute__((address_space(3))) u32*)l, 16, 0, 0);
}

__device__ __forceinline__ float gelu_f(float v) {
    return 0.5f * v * (1.0f + erff(v * 0.70710678118654752f));
}

// ---------------- LayerNorm: f32 in -> bf16 out ----------------
__global__ __launch_bounds__(256) void ln_bf16_k(const float* __restrict__ x,
                                                 const float* __restrict__ g,
                                                 const float* __restrict__ b,
                                                 u16* __restrict__ y) {
    int row = blockIdx.x;
    int tid = threadIdx.x;
    const float* xr = x + (size_t)row * D_;
    f32x4 v = *(const f32x4*)(xr + tid * 4);
    float s = v.x + v.y + v.z + v.w;
    float ss = v.x * v.x + v.y * v.y + v.z * v.z + v.w * v.w;
    for (int off = 32; off > 0; off >>= 1) {
        s += __shfl_down(s, off, 64);
        ss += __shfl_down(ss, off, 64);
    }
    __shared__ float rs[4], rss[4];
    int lane = tid & 63, wid = tid >> 6;
    if (lane == 0) { rs[wid] = s; rss[wid] = ss; }
    __syncthreads();
    s = rs[0] + rs[1] + rs[2] + rs[3];
    ss = rss[0] + rss[1] + rss[2] + rss[3];
    float mu = s * (1.0f / D_);
    float var = ss * (1.0f / D_) - mu * mu;
    float inv = rsqrtf(var + 1e-6f);
    f32x4 gg = *(const f32x4*)(g + tid * 4);
    f32x4 bb = *(const f32x4*)(b + tid * 4);
    bf16x4 o = {(__bf16)((v.x - mu) * inv * gg.x + bb.x),
                (__bf16)((v.y - mu) * inv * gg.y + bb.y),
                (__bf16)((v.z - mu) * inv * gg.z + bb.z),
                (__bf16)((v.w - mu) * inv * gg.w + bb.w)};
    *(bf16x4*)(y + (size_t)row * D_ + tid * 4) = o;
}

// ---------------- bias pack: bqkv = [bq|bk|bv] ----------------
__global__ void pack3_k(const float* __restrict__ a, const float* __restrict__ b,
                        const float* __restrict__ c, float* __restrict__ o) {
    const float* s = blockIdx.x == 0 ? a : (blockIdx.x == 1 ? b : c);
    o[blockIdx.x * 1024 + threadIdx.x] = s[threadIdx.x];
}

// ---------------- weight transpose+convert: W[K,N] f32 -> Wt[N,K] bf16 ----------------
__global__ __launch_bounds__(256) void wtrans_k(const float* __restrict__ W,
                                                u16* __restrict__ Wt, int K, int N) {
    __shared__ float T[32][33];
    int tid = threadIdx.x;
    int k0 = blockIdx.y * 32, n0 = blockIdx.x * 32;
    int r = tid >> 3, c4 = (tid & 7) * 4;
    f32x4 v = *(const f32x4*)&W[(size_t)(k0 + r) * N + n0 + c4];
    T[r][c4 + 0] = v.x; T[r][c4 + 1] = v.y; T[r][c4 + 2] = v.z; T[r][c4 + 3] = v.w;
    __syncthreads();
    int n = tid >> 3, kk = (tid & 7) * 4;
    bf16x4 o = {(__bf16)T[kk + 0][n], (__bf16)T[kk + 1][n],
                (__bf16)T[kk + 2][n], (__bf16)T[kk + 3][n]};
    *(bf16x4*)&Wt[(size_t)(n0 + n) * K + k0 + kk] = o;
}

// ---------------- V transpose: QKV bf16 [B*S,3072] (V cols) -> Vt bf16 [B*H*64][S] ----------------
__global__ __launch_bounds__(256) void vtrans_k(const u16* __restrict__ QKV,
                                                u16* __restrict__ Vt) {
    __shared__ u16 T[64][80];
    int tid = threadIdx.x;
    int s0 = blockIdx.x * 64;
    int bh = blockIdx.y, b = bh >> 4, h = bh & 15;
    int r = tid >> 2, c0 = (tid & 3) * 16;
    const u16* src = QKV + (size_t)(b * S_ + s0 + r) * 3072 + 2048 + h * 64 + c0;
    us8 v0 = *(const us8*)src;
    us8 v1 = *(const us8*)(src + 8);
    *(us8*)&T[r][c0] = v0;
    *(us8*)&T[r][c0 + 8] = v1;
    __syncthreads();
    int dh = tid >> 2, s8 = (tid & 3) * 16;
    us8 o0, o1;
#pragma unroll
    for (int i = 0; i < 8; ++i) { o0[i] = T[s8 + i][dh]; o1[i] = T[s8 + 8 + i][dh]; }
    u16* dst = Vt + (size_t)(bh * 64 + dh) * S_ + s0 + s8;
    *(us8*)dst = o0;
    *(us8*)(dst + 8) = o1;
}

// ---------------- bf16 MFMA GEMM: C[M,N] = A[M,K] @ Wt[N,K]^T (+epilogue) ----------------
// EPI: 0 = +bias -> bf16 ; 1 = gelu(+bias) -> bf16 ; 2 = +bias +res -> f32
template <int EPI>
__global__ __launch_bounds__(256) void gemm_bf16(const u16* __restrict__ A,
                                                 const u16* __restrict__ Wt,
                                                 const float* __restrict__ bias,
                                                 const float* __restrict__ res,
                                                 void* __restrict__ Cout,
                                                 int M, int N, int K) {
    __shared__ u16 As[128 * 32];
    __shared__ u16 Bs[128 * 32];
    const int tid = threadIdx.x;
    const int lane = tid & 63;
    const int w = tid >> 6;
    // XCD-chunked bijective remap (nwg % 8 == 0 for all our grids)
    const int nwg = gridDim.x * gridDim.y;
    int hw = blockIdx.x + gridDim.x * blockIdx.y;
    int lg = (hw & 7) * (nwg >> 3) + (hw >> 3);
    const int row0 = (lg / gridDim.x) * 128;
    const int col0 = (lg % gridDim.x) * 128;
    const int l15 = lane & 15, l16 = lane >> 4;
    const int wr = w >> 1, wc = w & 1;

    f32x4 acc[4][4];
#pragma unroll
    for (int i = 0; i < 4; ++i)
#pragma unroll
        for (int j = 0; j < 4; ++j) acc[i][j] = (f32x4){0.f, 0.f, 0.f, 0.f};

    const int srow = w * 32 + (lane >> 2);
    const size_t sboff = (size_t)(lane & 3) * 16;
    const char* Ag = (const char*)A + ((size_t)(row0 + srow) * K) * 2 + sboff;
    const char* Bg = (const char*)Wt + ((size_t)(col0 + srow) * K) * 2 + sboff;
    const size_t rstep = (size_t)16 * K * 2;
    char* AsW = (char*)As + (w * 32) * 64;
    char* BsW = (char*)Bs + (w * 32) * 64;

    for (int k0 = 0; k0 < K; k0 += 32) {
        size_t kb = (size_t)k0 * 2;
        gload16(Ag + kb, AsW);
        gload16(Ag + kb + rstep, AsW + 1024);
        gload16(Bg + kb, BsW);
        gload16(Bg + kb + rstep, BsW + 1024);
        __syncthreads();
        bf16x8 af[4], bfr[4];
#pragma unroll
        for (int f = 0; f < 4; ++f) {
            af[f] = *(const bf16x8*)((const char*)As + (size_t)(wr * 64 + f * 16 + l15) * 64 + (l16 << 4));
            bfr[f] = *(const bf16x8*)((const char*)Bs + (size_t)(wc * 64 + f * 16 + l15) * 64 + (l16 << 4));
        }
#pragma unroll
        for (int fi = 0; fi < 4; ++fi)
#pragma unroll
            for (int fj = 0; fj < 4; ++fj)
                acc[fi][fj] = __builtin_amdgcn_mfma_f32_16x16x32_bf16(af[fi], bfr[fj], acc[fi][fj], 0, 0, 0);
        __syncthreads();
    }

    const int rb = row0 + wr * 64 + (l16 << 2);
    const int cb = col0 + wc * 64 + l15;
#pragma unroll
    for (int fi = 0; fi < 4; ++fi)
#pragma unroll
        for (int fj = 0; fj < 4; ++fj) {
            int c = cb + fj * 16;
            float bv = bias[c];
#pragma unroll
            for (int rr = 0; rr < 4; ++rr) {
                int r = rb + fi * 16 + rr;
                float v = acc[fi][fj][rr] + bv;
                if (EPI == 1) v = gelu_f(v);
                if (EPI == 2) {
                    v += res[(size_t)r * N + c];
                    ((float*)Cout)[(size_t)r * N + c] = v;
                } else {
                    ((__bf16*)Cout)[(size_t)r * N + c] = (__bf16)v;
                }
            }
        }
}

// ---------------- MFMA flash attention (2-phase pipelined) ----------------
// grid (32, 64) remapped; block 256 (4 waves, 16 query-rows each).
__global__ __launch_bounds__(256) void attn_mfma(const u16* __restrict__ QKV,
                                                 const u16* __restrict__ Vt,
                                                 u16* __restrict__ O) {
    __shared__ u16 Ks[2][64 * 64];
    __shared__ u16 Vs[2][64 * 64];
    __shared__ u16 Ps[4][16 * 64];
    const int tid = threadIdx.x, lane = tid & 63, w = tid >> 6;
    // XCD clustering: each XCD owns 8 consecutive bh (its K/V slice = 4MB = L2)
    int hw = blockIdx.x + gridDim.x * blockIdx.y;
    int lg = (hw & 7) * 256 + (hw >> 3);
    const int bh = lg >> 5, b = bh >> 4, h = bh & 15;
    const int q0 = (lg & 31) * 64;
    const int l15 = lane & 15, l16 = lane >> 4;

    const u16* Qp = QKV + (size_t)(b * S_ + q0 + w * 16 + l15) * 3072 + h * 64 + (l16 << 3);
    bf16x8 qf0 = *(const bf16x8*)Qp;
    bf16x8 qf1 = *(const bf16x8*)(Qp + 32);

    f32x4 oacc[4];
#pragma unroll
    for (int i = 0; i < 4; ++i) oacc[i] = (f32x4){0.f, 0.f, 0.f, 0.f};
    float mold[4] = {-1e30f, -1e30f, -1e30f, -1e30f};
    float lsum[4] = {0.f, 0.f, 0.f, 0.f};

    const int sr = lane >> 3;
    const size_t soff = (size_t)(((lane & 7) ^ sr) << 4);  // pre-swizzled source chunk
    const char* Kg = (const char*)QKV + ((size_t)b * S_ * 3072 + 1024 + h * 64) * 2;
    const char* Vg = (const char*)Vt + (size_t)bh * 64 * S_ * 2;
    char* Pw = (char*)Ps[w];
    const float C2 = 0.18033688011112f;   // 0.125 * log2(e)
    const float THRRAW = 44.0f;           // ~8 nats in raw-score units

    auto stage = [&](int kt, int bi) {
#pragma unroll
        for (int i = 0; i < 2; ++i) {
            int rbase = w * 16 + i * 8;
            gload16(Kg + (size_t)(kt * 64 + rbase + sr) * 6144 + soff, (char*)Ks[bi] + rbase * 128);
            gload16(Vg + (size_t)(rbase + sr) * (S_ * 2) + (size_t)kt * 128 + soff, (char*)Vs[bi] + rbase * 128);
        }
    };

    stage(0, 0);
    __syncthreads();

    for (int kt = 0; kt < S_ / 64; ++kt) {
        const int cur = kt & 1;
        if (kt < S_ / 64 - 1) stage(kt + 1, cur ^ 1);   // prefetch overlaps compute

        // S = Q @ K^T  (per wave: 16 q-rows x 64 keys)
        f32x4 sfr[4];
        const char* Kb_ = (const char*)Ks[cur];
        __builtin_amdgcn_s_setprio(1);
#pragma unroll
        for (int cf = 0; cf < 4; ++cf) {
            int r = cf * 16 + l15;
            int x0 = (l16 << 4) ^ ((r & 7) << 4);
            bf16x8 k0v = *(const bf16x8*)(Kb_ + r * 128 + x0);
            bf16x8 k1v = *(const bf16x8*)(Kb_ + r * 128 + (x0 ^ 64));
            f32x4 t = (f32x4){0.f, 0.f, 0.f, 0.f};
            t = __builtin_amdgcn_mfma_f32_16x16x32_bf16(qf0, k0v, t, 0, 0, 0);
            t = __builtin_amdgcn_mfma_f32_16x16x32_bf16(qf1, k1v, t, 0, 0, 0);
            sfr[cf] = t;
        }
        __builtin_amdgcn_s_setprio(0);

        // row maxima (raw units)
        float cmax[4];
#pragma unroll
        for (int rr = 0; rr < 4; ++rr) {
            float mx = fmaxf(fmaxf(sfr[0][rr], sfr[1][rr]), fmaxf(sfr[2][rr], sfr[3][rr]));
#pragma unroll
            for (int d = 1; d < 16; d <<= 1) mx = fmaxf(mx, __shfl_xor(mx, d, 64));
            cmax[rr] = mx;
        }
        // defer-max: rescale only when some row max grew past threshold
        bool need = (cmax[0] > mold[0] + THRRAW) || (cmax[1] > mold[1] + THRRAW) ||
                    (cmax[2] > mold[2] + THRRAW) || (cmax[3] > mold[3] + THRRAW);
        if (__any(need)) {
#pragma unroll
            for (int rr = 0; rr < 4; ++rr) {
                float mnew = fmaxf(mold[rr], cmax[rr]);
                float al = exp2f((mold[rr] - mnew) * C2);
                lsum[rr] *= al;
                mold[rr] = mnew;
#pragma unroll
                for (int fj = 0; fj < 4; ++fj) oacc[fj][rr] *= al;
            }
        }
        // P = exp2(C2*s - C2*m), row sums, P -> LDS (bf16, swizzled, per-wave buffer)
#pragma unroll
        for (int rr = 0; rr < 4; ++rr) {
            float nm = -mold[rr] * C2;
            float p0 = exp2f(fmaf(sfr[0][rr], C2, nm));
            float p1 = exp2f(fmaf(sfr[1][rr], C2, nm));
            float p2 = exp2f(fmaf(sfr[2][rr], C2, nm));
            float p3 = exp2f(fmaf(sfr[3][rr], C2, nm));
            float rsv = (p0 + p1) + (p2 + p3);
#pragma unroll
            for (int d = 1; d < 16; d <<= 1) rsv += __shfl_xor(rsv, d, 64);
            lsum[rr] += rsv;
            int prow = (l16 << 2) + rr;
            char* Pr = Pw + prow * 128;
            int sw = (prow & 7) << 4;
            *(__bf16*)(Pr + (((0 * 16 + l15) * 2) ^ sw)) = (__bf16)p0;
            *(__bf16*)(Pr + (((1 * 16 + l15) * 2) ^ sw)) = (__bf16)p1;
            *(__bf16*)(Pr + (((2 * 16 + l15) * 2) ^ sw)) = (__bf16)p2;
            *(__bf16*)(Pr + (((3 * 16 + l15) * 2) ^ sw)) = (__bf16)p3;
        }

        // O += P @ V
        {
            const char* Vb_ = (const char*)Vs[cur];
            int prow = l15;
            int x0 = (l16 << 4) ^ ((prow & 7) << 4);
            bf16x8 pf0 = *(const bf16x8*)(Pw + prow * 128 + x0);
            bf16x8 pf1 = *(const bf16x8*)(Pw + prow * 128 + (x0 ^ 64));
            __builtin_amdgcn_s_setprio(1);
#pragma unroll
            for (int fj = 0; fj < 4; ++fj) {
                int vr = fj * 16 + l15;
                int y0 = (l16 << 4) ^ ((vr & 7) << 4);
                bf16x8 v0 = *(const bf16x8*)(Vb_ + vr * 128 + y0);
                bf16x8 v1 = *(const bf16x8*)(Vb_ + vr * 128 + (y0 ^ 64));
                oacc[fj] = __builtin_amdgcn_mfma_f32_16x16x32_bf16(pf0, v0, oacc[fj], 0, 0, 0);
                oacc[fj] = __builtin_amdgcn_mfma_f32_16x16x32_bf16(pf1, v1, oacc[fj], 0, 0, 0);
            }
            __builtin_amdgcn_s_setprio(0);
        }
        __syncthreads();   // drains prefetch vmcnt + protects buffer swap
    }

    float inv[4];
#pragma unroll
    for (int rr = 0; rr < 4; ++rr) inv[rr] = 1.0f / lsum[rr];
#pragma unroll
    for (int fj = 0; fj < 4; ++fj)
#pragma unroll
        for (int rr = 0; rr < 4; ++rr) {
            int r = b * S_ + q0 + w * 16 + (l16 << 2) + rr;
            ((__bf16*)O)[(size_t)r * D_ + h * 64 + fj * 16 + l15] = (__bf16)(oacc[fj][rr] * inv[rr]);
        }
}

// ---------------- launch ----------------
extern "C" void kernel_launch(void* const* d_in, const int* in_sizes, int n_in,
                              void* d_out, int out_size, void* d_ws, size_t ws_size,
                              hipStream_t stream) {
    const float* x     = (const float*)d_in[0];
    const float* Wq    = (const float*)d_in[1];
    const float* bq    = (const float*)d_in[2];
    const float* Wk    = (const float*)d_in[3];
    const float* bk    = (const float*)d_in[4];
    const float* Wv    = (const float*)d_in[5];
    const float* bv    = (const float*)d_in[6];
    const float* Wo    = (const float*)d_in[7];
    const float* bo    = (const float*)d_in[8];
    const float* ln1_g = (const float*)d_in[9];
    const float* ln1_b = (const float*)d_in[10];
    const float* ln2_g = (const float*)d_in[11];
    const float* ln2_b = (const float*)d_in[12];
    const float* W1    = (const float*)d_in[13];
    const float* b1    = (const float*)d_in[14];
    const float* W2    = (const float*)d_in[15];
    const float* b2    = (const float*)d_in[16];
    float* out = (float*)d_out;

    const size_t MB = 1ull << 20;
    char* ws = (char*)d_ws;
    u16* QKVb = (u16*)(ws + 0 * MB);      // 48MB [8192][3072]
    u16* aout = (u16*)(ws + 48 * MB);     // 16MB [8192][1024]
    u16* mid  = (u16*)(ws + 0 * MB);      // 64MB [8192][4096] (reuses QKVb+aout after out-proj)
    float* x2 = (float*)(ws + 64 * MB);   // 32MB f32
    float* bqkv = (float*)(ws + 64 * MB); // 12KB (dead once x2 is written)
    u16* xn   = (u16*)(ws + 96 * MB);     // 16MB
    u16* Vt   = (u16*)(ws + 96 * MB);     // 16MB (reuses xn after QKV)
    u16* xn2  = (u16*)(ws + 96 * MB);     // 16MB (reuses Vt after attn)
    u16* Wqkvt = (u16*)(ws + 112 * MB);   // 6MB [3072][1024]
    u16* Wot  = Wqkvt + (size_t)3072 * D_;// 2MB
    u16* W1t  = (u16*)(ws + 112 * MB);    // 8MB (reuses Wqkvt+Wot after out-proj)
    u16* W2t  = (u16*)(ws + 120 * MB);    // 8MB

    // weight conversions + bias pack
    wtrans_k<<<dim3(32, 32), 256, 0, stream>>>(Wq, Wqkvt, D_, D_);
    wtrans_k<<<dim3(32, 32), 256, 0, stream>>>(Wk, Wqkvt + (size_t)D_ * D_, D_, D_);
    wtrans_k<<<dim3(32, 32), 256, 0, stream>>>(Wv, Wqkvt + (size_t)2 * D_ * D_, D_, D_);
    wtrans_k<<<dim3(32, 32), 256, 0, stream>>>(Wo, Wot, D_, D_);
    wtrans_k<<<dim3(32, 128), 256, 0, stream>>>(W2, W2t, MLP_, D_);
    pack3_k<<<3, 1024, 0, stream>>>(bq, bk, bv, bqkv);

    // LN1
    ln_bf16_k<<<MROWS, 256, 0, stream>>>(x, ln1_g, ln1_b, xn);
    // fused QKV projection: [8192][3072]
    gemm_bf16<0><<<dim3(24, 64), 256, 0, stream>>>(xn, Wqkvt, bqkv, nullptr, QKVb, MROWS, 3072, D_);
    // V transpose per head
    vtrans_k<<<dim3(32, 64), 256, 0, stream>>>(QKVb, Vt);
    // attention
    attn_mfma<<<dim3(32, 64), 256, 0, stream>>>(QKVb, Vt, aout);
    // out projection + residual -> x2 (f32)
    gemm_bf16<2><<<dim3(8, 64), 256, 0, stream>>>(aout, Wot, bo, x, x2, MROWS, D_, D_);
    // W1 transpose (Wqkvt/Wot now dead), LN2
    wtrans_k<<<dim3(128, 32), 256, 0, stream>>>(W1, W1t, D_, MLP_);
    ln_bf16_k<<<MROWS, 256, 0, stream>>>(x2, ln2_g, ln2_b, xn2);
    // MLP
    gemm_bf16<1><<<dim3(32, 64), 256, 0, stream>>>(xn2, W1t, b1, nullptr, mid, MROWS, MLP_, D_);
    gemm_bf16<2><<<dim3(8, 64), 256, 0, stream>>>(mid, W2t, b2, x2, (void*)out, MROWS, D_, MLP_);
}

// Round 4
// 530.262 us; speedup vs baseline: 8.5185x; 1.1143x over previous
//
#include <hip/hip_runtime.h>
#include <math.h>

#define B_ 4
#define S_ 2048
#define D_ 1024
#define H_ 16
#define MLP_ 4096
#define MROWS 8192

typedef __attribute__((ext_vector_type(4))) float f32x4;
typedef __attribute__((ext_vector_type(8))) __bf16 bf16x8;
typedef __attribute__((ext_vector_type(4))) __bf16 bf16x4;
typedef __attribute__((ext_vector_type(8))) unsigned short us8;
typedef unsigned short u16;
typedef unsigned int u32;

__device__ __forceinline__ void gload16(const void* g, void* l) {
    __builtin_amdgcn_global_load_lds((const __attribute__((address_space(1))) u32*)g,
                                     (__attribute__((address_space(3))) u32*)l, 16, 0, 0);
}

__device__ __forceinline__ float gelu_f(float v) {
    return 0.5f * v * (1.0f + erff(v * 0.70710678118654752f));
}

// ---------------- LayerNorm: f32 in -> bf16 out ----------------
__global__ __launch_bounds__(256) void ln_bf16_k(const float* __restrict__ x,
                                                 const float* __restrict__ g,
                                                 const float* __restrict__ b,
                                                 u16* __restrict__ y) {
    int row = blockIdx.x;
    int tid = threadIdx.x;
    const float* xr = x + (size_t)row * D_;
    f32x4 v = *(const f32x4*)(xr + tid * 4);
    float s = v.x + v.y + v.z + v.w;
    float ss = v.x * v.x + v.y * v.y + v.z * v.z + v.w * v.w;
    for (int off = 32; off > 0; off >>= 1) {
        s += __shfl_down(s, off, 64);
        ss += __shfl_down(ss, off, 64);
    }
    __shared__ float rs[4], rss[4];
    int lane = tid & 63, wid = tid >> 6;
    if (lane == 0) { rs[wid] = s; rss[wid] = ss; }
    __syncthreads();
    s = rs[0] + rs[1] + rs[2] + rs[3];
    ss = rss[0] + rss[1] + rss[2] + rss[3];
    float mu = s * (1.0f / D_);
    float var = ss * (1.0f / D_) - mu * mu;
    float inv = rsqrtf(var + 1e-6f);
    f32x4 gg = *(const f32x4*)(g + tid * 4);
    f32x4 bb = *(const f32x4*)(b + tid * 4);
    bf16x4 o = {(__bf16)((v.x - mu) * inv * gg.x + bb.x),
                (__bf16)((v.y - mu) * inv * gg.y + bb.y),
                (__bf16)((v.z - mu) * inv * gg.z + bb.z),
                (__bf16)((v.w - mu) * inv * gg.w + bb.w)};
    *(bf16x4*)(y + (size_t)row * D_ + tid * 4) = o;
}

// ---------------- bias pack: bqkv = [bq|bk|bv] ----------------
__global__ void pack3_k(const float* __restrict__ a, const float* __restrict__ b,
                        const float* __restrict__ c, float* __restrict__ o) {
    const float* s = blockIdx.x == 0 ? a : (blockIdx.x == 1 ? b : c);
    o[blockIdx.x * 1024 + threadIdx.x] = s[threadIdx.x];
}

// ---------------- weight transpose+convert: W[K,N] f32 -> Wt[N,K] bf16 ----------------
__global__ __launch_bounds__(256) void wtrans_k(const float* __restrict__ W,
                                                u16* __restrict__ Wt, int K, int N) {
    __shared__ float T[32][33];
    int tid = threadIdx.x;
    int k0 = blockIdx.y * 32, n0 = blockIdx.x * 32;
    int r = tid >> 3, c4 = (tid & 7) * 4;
    f32x4 v = *(const f32x4*)&W[(size_t)(k0 + r) * N + n0 + c4];
    T[r][c4 + 0] = v.x; T[r][c4 + 1] = v.y; T[r][c4 + 2] = v.z; T[r][c4 + 3] = v.w;
    __syncthreads();
    int n = tid >> 3, kk = (tid & 7) * 4;
    bf16x4 o = {(__bf16)T[kk + 0][n], (__bf16)T[kk + 1][n],
                (__bf16)T[kk + 2][n], (__bf16)T[kk + 3][n]};
    *(bf16x4*)&Wt[(size_t)(n0 + n) * K + k0 + kk] = o;
}

// ---------------- V transpose: QKV bf16 [B*S,3072] (V cols) -> Vt bf16 [B*H*64][S] ----------------
__global__ __launch_bounds__(256) void vtrans_k(const u16* __restrict__ QKV,
                                                u16* __restrict__ Vt) {
    __shared__ u16 T[64][80];
    int tid = threadIdx.x;
    int s0 = blockIdx.x * 64;
    int bh = blockIdx.y, b = bh >> 4, h = bh & 15;
    int r = tid >> 2, c0 = (tid & 3) * 16;
    const u16* src = QKV + (size_t)(b * S_ + s0 + r) * 3072 + 2048 + h * 64 + c0;
    us8 v0 = *(const us8*)src;
    us8 v1 = *(const us8*)(src + 8);
    *(us8*)&T[r][c0] = v0;
    *(us8*)&T[r][c0 + 8] = v1;
    __syncthreads();
    int dh = tid >> 2, s8 = (tid & 3) * 16;
    us8 o0, o1;
#pragma unroll
    for (int i = 0; i < 8; ++i) { o0[i] = T[s8 + i][dh]; o1[i] = T[s8 + 8 + i][dh]; }
    u16* dst = Vt + (size_t)(bh * 64 + dh) * S_ + s0 + s8;
    *(us8*)dst = o0;
    *(us8*)(dst + 8) = o1;
}

// ---------------- bf16 MFMA GEMM: C[M,N] = A[M,K] @ Wt[N,K]^T (+epilogue) ----------------
// EPI: 0 = +bias -> bf16 ; 1 = gelu(+bias) -> bf16 ; 2 = +bias +res -> f32
template <int EPI>
__global__ __launch_bounds__(256) void gemm_bf16(const u16* __restrict__ A,
                                                 const u16* __restrict__ Wt,
                                                 const float* __restrict__ bias,
                                                 const float* __restrict__ res,
                                                 void* __restrict__ Cout,
                                                 int M, int N, int K) {
    __shared__ u16 As[128 * 32];
    __shared__ u16 Bs[128 * 32];
    const int tid = threadIdx.x;
    const int lane = tid & 63;
    const int w = tid >> 6;
    // XCD-chunked bijective remap (nwg % 8 == 0 for all our grids)
    const int nwg = gridDim.x * gridDim.y;
    int hw = blockIdx.x + gridDim.x * blockIdx.y;
    int lg = (hw & 7) * (nwg >> 3) + (hw >> 3);
    const int row0 = (lg / gridDim.x) * 128;
    const int col0 = (lg % gridDim.x) * 128;
    const int l15 = lane & 15, l16 = lane >> 4;
    const int wr = w >> 1, wc = w & 1;

    f32x4 acc[4][4];
#pragma unroll
    for (int i = 0; i < 4; ++i)
#pragma unroll
        for (int j = 0; j < 4; ++j) acc[i][j] = (f32x4){0.f, 0.f, 0.f, 0.f};

    const int srow = w * 32 + (lane >> 2);
    const size_t sboff = (size_t)(lane & 3) * 16;
    const char* Ag = (const char*)A + ((size_t)(row0 + srow) * K) * 2 + sboff;
    const char* Bg = (const char*)Wt + ((size_t)(col0 + srow) * K) * 2 + sboff;
    const size_t rstep = (size_t)16 * K * 2;
    char* AsW = (char*)As + (w * 32) * 64;
    char* BsW = (char*)Bs + (w * 32) * 64;

    for (int k0 = 0; k0 < K; k0 += 32) {
        size_t kb = (size_t)k0 * 2;
        gload16(Ag + kb, AsW);
        gload16(Ag + kb + rstep, AsW + 1024);
        gload16(Bg + kb, BsW);
        gload16(Bg + kb + rstep, BsW + 1024);
        __syncthreads();
        bf16x8 af[4], bfr[4];
#pragma unroll
        for (int f = 0; f < 4; ++f) {
            af[f] = *(const bf16x8*)((const char*)As + (size_t)(wr * 64 + f * 16 + l15) * 64 + (l16 << 4));
            bfr[f] = *(const bf16x8*)((const char*)Bs + (size_t)(wc * 64 + f * 16 + l15) * 64 + (l16 << 4));
        }
#pragma unroll
        for (int fi = 0; fi < 4; ++fi)
#pragma unroll
            for (int fj = 0; fj < 4; ++fj)
                acc[fi][fj] = __builtin_amdgcn_mfma_f32_16x16x32_bf16(af[fi], bfr[fj], acc[fi][fj], 0, 0, 0);
        __syncthreads();
    }

    const int rb = row0 + wr * 64 + (l16 << 2);
    const int cb = col0 + wc * 64 + l15;
#pragma unroll
    for (int fi = 0; fi < 4; ++fi)
#pragma unroll
        for (int fj = 0; fj < 4; ++fj) {
            int c = cb + fj * 16;
            float bv = bias[c];
#pragma unroll
            for (int rr = 0; rr < 4; ++rr) {
                int r = rb + fi * 16 + rr;
                float v = acc[fi][fj][rr] + bv;
                if (EPI == 1) v = gelu_f(v);
                if (EPI == 2) {
                    v += res[(size_t)r * N + c];
                    ((float*)Cout)[(size_t)r * N + c] = v;
                } else {
                    ((__bf16*)Cout)[(size_t)r * N + c] = (__bf16)v;
                }
            }
        }
}

// ---------------- MFMA flash attention (swapped-QK lane-local softmax) ----------------
// grid (32, 64) remapped; block 256 (4 waves, 16 query-rows each).
__global__ __launch_bounds__(256) void attn_mfma(const u16* __restrict__ QKV,
                                                 const u16* __restrict__ Vt,
                                                 u16* __restrict__ O) {
    __shared__ u16 Ks[2][64 * 64];
    __shared__ u16 Vs[2][64 * 64];
    __shared__ u16 Ps[4][16 * 64];
    const int tid = threadIdx.x, lane = tid & 63, w = tid >> 6;
    // XCD clustering: each XCD owns 8 consecutive bh (its K/V slice = 4MB = L2)
    int hw = blockIdx.x + gridDim.x * blockIdx.y;
    int lg = (hw & 7) * 256 + (hw >> 3);
    const int bh = lg >> 5, b = bh >> 4, h = bh & 15;
    const int q0 = (lg & 31) * 64;
    const int l15 = lane & 15, l16 = lane >> 4;

    const u16* Qp = QKV + (size_t)(b * S_ + q0 + w * 16 + l15) * 3072 + h * 64 + (l16 << 3);
    bf16x8 qf0 = *(const bf16x8*)Qp;
    bf16x8 qf1 = *(const bf16x8*)(Qp + 32);

    f32x4 oacc[4];
#pragma unroll
    for (int i = 0; i < 4; ++i) oacc[i] = (f32x4){0.f, 0.f, 0.f, 0.f};
    // per-lane softmax state for query l15 (replicated over the 4 l16 groups)
    float mold_l = -1e30f, lsum_l = 0.f;

    const int sr = lane >> 3;
    const size_t soff = (size_t)(((lane & 7) ^ sr) << 4);  // pre-swizzled source chunk
    const char* Kg = (const char*)QKV + ((size_t)b * S_ * 3072 + 1024 + h * 64) * 2;
    const char* Vg = (const char*)Vt + (size_t)bh * 64 * S_ * 2;
    char* Pw = (char*)Ps[w];
    const float C2 = 0.18033688011112f;   // 0.125 * log2(e)
    const float THRRAW = 44.0f;           // ~5.5 nats in raw-score units

    auto stage = [&](int kt, int bi) {
#pragma unroll
        for (int i = 0; i < 2; ++i) {
            int rbase = w * 16 + i * 8;
            gload16(Kg + (size_t)(kt * 64 + rbase + sr) * 6144 + soff, (char*)Ks[bi] + rbase * 128);
            gload16(Vg + (size_t)(rbase + sr) * (S_ * 2) + (size_t)kt * 128 + soff, (char*)Vs[bi] + rbase * 128);
        }
    };

    stage(0, 0);
    __syncthreads();

    for (int kt = 0; kt < S_ / 64; ++kt) {
        const int cur = kt & 1;
        if (kt < S_ / 64 - 1) stage(kt + 1, cur ^ 1);   // prefetch overlaps compute

        // S^T = K @ Q^T  (per wave: 64 keys x 16 queries; col = query = l15)
        f32x4 sfr[4];
        const char* Kb_ = (const char*)Ks[cur];
        __builtin_amdgcn_s_setprio(1);
#pragma unroll
        for (int cf = 0; cf < 4; ++cf) {
            int r = cf * 16 + l15;
            int x0 = (l16 << 4) ^ ((r & 7) << 4);
            bf16x8 k0v = *(const bf16x8*)(Kb_ + r * 128 + x0);
            bf16x8 k1v = *(const bf16x8*)(Kb_ + r * 128 + (x0 ^ 64));
            f32x4 t = (f32x4){0.f, 0.f, 0.f, 0.f};
            t = __builtin_amdgcn_mfma_f32_16x16x32_bf16(k0v, qf0, t, 0, 0, 0);
            t = __builtin_amdgcn_mfma_f32_16x16x32_bf16(k1v, qf1, t, 0, 0, 0);
            sfr[cf] = t;   // sfr[cf][rr] = S[key = cf*16 + l16*4 + rr][query l15]
        }
        __builtin_amdgcn_s_setprio(0);

        // lane-local max over this lane's 16 keys, then 2-step cross-group reduce
        float mx = fmaxf(fmaxf(sfr[0][0], sfr[0][1]), fmaxf(sfr[0][2], sfr[0][3]));
        mx = fmaxf(mx, fmaxf(fmaxf(sfr[1][0], sfr[1][1]), fmaxf(sfr[1][2], sfr[1][3])));
        mx = fmaxf(mx, fmaxf(fmaxf(sfr[2][0], sfr[2][1]), fmaxf(sfr[2][2], sfr[2][3])));
        mx = fmaxf(mx, fmaxf(fmaxf(sfr[3][0], sfr[3][1]), fmaxf(sfr[3][2], sfr[3][3])));
        mx = fmaxf(mx, __shfl_xor(mx, 16, 64));
        mx = fmaxf(mx, __shfl_xor(mx, 32, 64));

        // defer-max: rescale only when this query's max grew past threshold
        bool need = mx > mold_l + THRRAW;
        if (__any(need)) {
            float mnew = fmaxf(mold_l, mx);
            float al = exp2f((mold_l - mnew) * C2);
            lsum_l *= al;
            mold_l = mnew;
#pragma unroll
            for (int rr = 0; rr < 4; ++rr) {
                float alq = __shfl(al, (l16 << 2) + rr, 64);  // stat lives in lane q (0..15)
#pragma unroll
                for (int fj = 0; fj < 4; ++fj) oacc[fj][rr] *= alq;
            }
        }

        // P = exp2(C2*s - C2*m): 16 lane-local values, lane-local sum + 2 shfl
        float nm = -mold_l * C2;
        float pv[4][4];
        float psum = 0.f;
#pragma unroll
        for (int cf = 0; cf < 4; ++cf)
#pragma unroll
            for (int rr = 0; rr < 4; ++rr) {
                float p = exp2f(fmaf(sfr[cf][rr], C2, nm));
                pv[cf][rr] = p;
                psum += p;
            }
        psum += __shfl_xor(psum, 16, 64);
        psum += __shfl_xor(psum, 32, 64);
        lsum_l += psum;

        // P -> LDS: row = query l15, keys cf*16 + l16*4 + rr are consecutive -> b64 writes
        {
            char* Pr = Pw + l15 * 128;
            const int sw = (l15 & 7) << 4;
#pragma unroll
            for (int cf = 0; cf < 4; ++cf) {
                bf16x4 pk = {(__bf16)pv[cf][0], (__bf16)pv[cf][1],
                             (__bf16)pv[cf][2], (__bf16)pv[cf][3]};
                *(bf16x4*)(Pr + ((cf * 32 + l16 * 8) ^ sw)) = pk;
            }
        }

        // O += P @ V
        {
            const char* Vb_ = (const char*)Vs[cur];
            int x0 = (l16 << 4) ^ ((l15 & 7) << 4);
            bf16x8 pf0 = *(const bf16x8*)(Pw + l15 * 128 + x0);
            bf16x8 pf1 = *(const bf16x8*)(Pw + l15 * 128 + (x0 ^ 64));
            __builtin_amdgcn_s_setprio(1);
#pragma unroll
            for (int fj = 0; fj < 4; ++fj) {
                int vr = fj * 16 + l15;
                int y0 = (l16 << 4) ^ ((vr & 7) << 4);
                bf16x8 v0 = *(const bf16x8*)(Vb_ + vr * 128 + y0);
                bf16x8 v1 = *(const bf16x8*)(Vb_ + vr * 128 + (y0 ^ 64));
                oacc[fj] = __builtin_amdgcn_mfma_f32_16x16x32_bf16(pf0, v0, oacc[fj], 0, 0, 0);
                oacc[fj] = __builtin_amdgcn_mfma_f32_16x16x32_bf16(pf1, v1, oacc[fj], 0, 0, 0);
            }
            __builtin_amdgcn_s_setprio(0);
        }
        __syncthreads();   // drains prefetch vmcnt + protects buffer swap
    }

    float inv_l = 1.0f / lsum_l;
    float invq[4];
#pragma unroll
    for (int rr = 0; rr < 4; ++rr) invq[rr] = __shfl(inv_l, (l16 << 2) + rr, 64);
#pragma unroll
    for (int fj = 0; fj < 4; ++fj)
#pragma unroll
        for (int rr = 0; rr < 4; ++rr) {
            int r = b * S_ + q0 + w * 16 + (l16 << 2) + rr;
            ((__bf16*)O)[(size_t)r * D_ + h * 64 + fj * 16 + l15] = (__bf16)(oacc[fj][rr] * invq[rr]);
        }
}

// ---------------- launch ----------------
extern "C" void kernel_launch(void* const* d_in, const int* in_sizes, int n_in,
                              void* d_out, int out_size, void* d_ws, size_t ws_size,
                              hipStream_t stream) {
    const float* x     = (const float*)d_in[0];
    const float* Wq    = (const float*)d_in[1];
    const float* bq    = (const float*)d_in[2];
    const float* Wk    = (const float*)d_in[3];
    const float* bk    = (const float*)d_in[4];
    const float* Wv    = (const float*)d_in[5];
    const float* bv    = (const float*)d_in[6];
    const float* Wo    = (const float*)d_in[7];
    const float* bo    = (const float*)d_in[8];
    const float* ln1_g = (const float*)d_in[9];
    const float* ln1_b = (const float*)d_in[10];
    const float* ln2_g = (const float*)d_in[11];
    const float* ln2_b = (const float*)d_in[12];
    const float* W1    = (const float*)d_in[13];
    const float* b1    = (const float*)d_in[14];
    const float* W2    = (const float*)d_in[15];
    const float* b2    = (const float*)d_in[16];
    float* out = (float*)d_out;

    const size_t MB = 1ull << 20;
    char* ws = (char*)d_ws;
    u16* QKVb = (u16*)(ws + 0 * MB);      // 48MB [8192][3072]
    u16* aout = (u16*)(ws + 48 * MB);     // 16MB [8192][1024]
    u16* mid  = (u16*)(ws + 0 * MB);      // 64MB [8192][4096] (reuses QKVb+aout after out-proj)
    float* x2 = (float*)(ws + 64 * MB);   // 32MB f32
    float* bqkv = (float*)(ws + 64 * MB); // 12KB (dead once x2 is written)
    u16* xn   = (u16*)(ws + 96 * MB);     // 16MB
    u16* Vt   = (u16*)(ws + 96 * MB);     // 16MB (reuses xn after QKV)
    u16* xn2  = (u16*)(ws + 96 * MB);     // 16MB (reuses Vt after attn)
    u16* Wqkvt = (u16*)(ws + 112 * MB);   // 6MB [3072][1024]
    u16* Wot  = Wqkvt + (size_t)3072 * D_;// 2MB
    u16* W1t  = (u16*)(ws + 112 * MB);    // 8MB (reuses Wqkvt+Wot after out-proj)
    u16* W2t  = (u16*)(ws + 120 * MB);    // 8MB

    // weight conversions + bias pack
    wtrans_k<<<dim3(32, 32), 256, 0, stream>>>(Wq, Wqkvt, D_, D_);
    wtrans_k<<<dim3(32, 32), 256, 0, stream>>>(Wk, Wqkvt + (size_t)D_ * D_, D_, D_);
    wtrans_k<<<dim3(32, 32), 256, 0, stream>>>(Wv, Wqkvt + (size_t)2 * D_ * D_, D_, D_);
    wtrans_k<<<dim3(32, 32), 256, 0, stream>>>(Wo, Wot, D_, D_);
    wtrans_k<<<dim3(32, 128), 256, 0, stream>>>(W2, W2t, MLP_, D_);
    pack3_k<<<3, 1024, 0, stream>>>(bq, bk, bv, bqkv);

    // LN1
    ln_bf16_k<<<MROWS, 256, 0, stream>>>(x, ln1_g, ln1_b, xn);
    // fused QKV projection: [8192][3072]
    gemm_bf16<0><<<dim3(24, 64), 256, 0, stream>>>(xn, Wqkvt, bqkv, nullptr, QKVb, MROWS, 3072, D_);
    // V transpose per head
    vtrans_k<<<dim3(32, 64), 256, 0, stream>>>(QKVb, Vt);
    // attention
    attn_mfma<<<dim3(32, 64), 256, 0, stream>>>(QKVb, Vt, aout);
    // out projection + residual -> x2 (f32)
    gemm_bf16<2><<<dim3(8, 64), 256, 0, stream>>>(aout, Wot, bo, x, x2, MROWS, D_, D_);
    // W1 transpose (Wqkvt/Wot now dead), LN2
    wtrans_k<<<dim3(128, 32), 256, 0, stream>>>(W1, W1t, D_, MLP_);
    ln_bf16_k<<<MROWS, 256, 0, stream>>>(x2, ln2_g, ln2_b, xn2);
    // MLP
    gemm_bf16<1><<<dim3(32, 64), 256, 0, stream>>>(xn2, W1t, b1, nullptr, mid, MROWS, MLP_, D_);
    gemm_bf16<2><<<dim3(8, 64), 256, 0, stream>>>(mid, W2t, b2, x2, (void*)out, MROWS, D_, MLP_);
}

// Round 5
// 503.997 us; speedup vs baseline: 8.9624x; 1.0521x over previous
//
#include <hip/hip_runtime.h>
#include <math.h>

#define B_ 4
#define S_ 2048
#define D_ 1024
#define H_ 16
#define MLP_ 4096
#define MROWS 8192

typedef __attribute__((ext_vector_type(4))) float f32x4;
typedef __attribute__((ext_vector_type(8))) __bf16 bf16x8;
typedef __attribute__((ext_vector_type(4))) __bf16 bf16x4;
typedef __attribute__((ext_vector_type(8))) unsigned short us8;
typedef unsigned short u16;
typedef unsigned int u32;

__device__ __forceinline__ void gload16(const void* g, void* l) {
    __builtin_amdgcn_global_load_lds((const __attribute__((address_space(1))) u32*)g,
                                     (__attribute__((address_space(3))) u32*)l, 16, 0, 0);
}

__device__ __forceinline__ float gelu_f(float v) {
    return 0.5f * v * (1.0f + erff(v * 0.70710678118654752f));
}

// ---------------- LayerNorm: f32 in -> bf16 out ----------------
__global__ __launch_bounds__(256) void ln_bf16_k(const float* __restrict__ x,
                                                 const float* __restrict__ g,
                                                 const float* __restrict__ b,
                                                 u16* __restrict__ y) {
    int row = blockIdx.x;
    int tid = threadIdx.x;
    const float* xr = x + (size_t)row * D_;
    f32x4 v = *(const f32x4*)(xr + tid * 4);
    float s = v.x + v.y + v.z + v.w;
    float ss = v.x * v.x + v.y * v.y + v.z * v.z + v.w * v.w;
    for (int off = 32; off > 0; off >>= 1) {
        s += __shfl_down(s, off, 64);
        ss += __shfl_down(ss, off, 64);
    }
    __shared__ float rs[4], rss[4];
    int lane = tid & 63, wid = tid >> 6;
    if (lane == 0) { rs[wid] = s; rss[wid] = ss; }
    __syncthreads();
    s = rs[0] + rs[1] + rs[2] + rs[3];
    ss = rss[0] + rss[1] + rss[2] + rss[3];
    float mu = s * (1.0f / D_);
    float var = ss * (1.0f / D_) - mu * mu;
    float inv = rsqrtf(var + 1e-6f);
    f32x4 gg = *(const f32x4*)(g + tid * 4);
    f32x4 bb = *(const f32x4*)(b + tid * 4);
    bf16x4 o = {(__bf16)((v.x - mu) * inv * gg.x + bb.x),
                (__bf16)((v.y - mu) * inv * gg.y + bb.y),
                (__bf16)((v.z - mu) * inv * gg.z + bb.z),
                (__bf16)((v.w - mu) * inv * gg.w + bb.w)};
    *(bf16x4*)(y + (size_t)row * D_ + tid * 4) = o;
}

// ---------------- bias pack: bqkv = [bq|bk|bv] ----------------
__global__ void pack3_k(const float* __restrict__ a, const float* __restrict__ b,
                        const float* __restrict__ c, float* __restrict__ o) {
    const float* s = blockIdx.x == 0 ? a : (blockIdx.x == 1 ? b : c);
    o[blockIdx.x * 1024 + threadIdx.x] = s[threadIdx.x];
}

// ---------------- weight transpose+convert: W[K,N] f32 -> Wt[N,K] bf16 ----------------
__global__ __launch_bounds__(256) void wtrans_k(const float* __restrict__ W,
                                                u16* __restrict__ Wt, int K, int N) {
    __shared__ float T[32][33];
    int tid = threadIdx.x;
    int k0 = blockIdx.y * 32, n0 = blockIdx.x * 32;
    int r = tid >> 3, c4 = (tid & 7) * 4;
    f32x4 v = *(const f32x4*)&W[(size_t)(k0 + r) * N + n0 + c4];
    T[r][c4 + 0] = v.x; T[r][c4 + 1] = v.y; T[r][c4 + 2] = v.z; T[r][c4 + 3] = v.w;
    __syncthreads();
    int n = tid >> 3, kk = (tid & 7) * 4;
    bf16x4 o = {(__bf16)T[kk + 0][n], (__bf16)T[kk + 1][n],
                (__bf16)T[kk + 2][n], (__bf16)T[kk + 3][n]};
    *(bf16x4*)&Wt[(size_t)(n0 + n) * K + k0 + kk] = o;
}

// ---------------- V transpose: QKV bf16 [B*S,3072] (V cols) -> Vt bf16 [B*H*64][S] ----------------
__global__ __launch_bounds__(256) void vtrans_k(const u16* __restrict__ QKV,
                                                u16* __restrict__ Vt) {
    __shared__ u16 T[64][80];
    int tid = threadIdx.x;
    int s0 = blockIdx.x * 64;
    int bh = blockIdx.y, b = bh >> 4, h = bh & 15;
    int r = tid >> 2, c0 = (tid & 3) * 16;
    const u16* src = QKV + (size_t)(b * S_ + s0 + r) * 3072 + 2048 + h * 64 + c0;
    us8 v0 = *(const us8*)src;
    us8 v1 = *(const us8*)(src + 8);
    *(us8*)&T[r][c0] = v0;
    *(us8*)&T[r][c0 + 8] = v1;
    __syncthreads();
    int dh = tid >> 2, s8 = (tid & 3) * 16;
    us8 o0, o1;
#pragma unroll
    for (int i = 0; i < 8; ++i) { o0[i] = T[s8 + i][dh]; o1[i] = T[s8 + 8 + i][dh]; }
    u16* dst = Vt + (size_t)(bh * 64 + dh) * S_ + s0 + s8;
    *(us8*)dst = o0;
    *(us8*)(dst + 8) = o1;
}

// ---------------- bf16 MFMA GEMM, depth-2 prefetch pipeline ----------------
// C[M,N] = A[M,K] @ Wt[N,K]^T (+epilogue)
// EPI: 0 = +bias -> bf16 ; 1 = gelu(+bias) -> bf16 ; 2 = +bias +res -> f32
template <int EPI>
__global__ __launch_bounds__(256) void gemm_bf16(const u16* __restrict__ A,
                                                 const u16* __restrict__ Wt,
                                                 const float* __restrict__ bias,
                                                 const float* __restrict__ res,
                                                 void* __restrict__ Cout,
                                                 int M, int N, int K) {
    __shared__ u16 As[3][128 * 32];   // 3-deep rotation, 8KB each
    __shared__ u16 Bs[3][128 * 32];
    const int tid = threadIdx.x;
    const int lane = tid & 63;
    const int w = tid >> 6;
    // XCD-chunked bijective remap (nwg % 8 == 0 for all our grids)
    const int nwg = gridDim.x * gridDim.y;
    int hw = blockIdx.x + gridDim.x * blockIdx.y;
    int lg = (hw & 7) * (nwg >> 3) + (hw >> 3);
    const int row0 = (lg / gridDim.x) * 128;
    const int col0 = (lg % gridDim.x) * 128;
    const int l15 = lane & 15, l16 = lane >> 4;
    const int wr = w >> 1, wc = w & 1;

    f32x4 acc[4][4];
#pragma unroll
    for (int i = 0; i < 4; ++i)
#pragma unroll
        for (int j = 0; j < 4; ++j) acc[i][j] = (f32x4){0.f, 0.f, 0.f, 0.f};

    const int srow = w * 32 + (lane >> 2);
    const size_t sboff = (size_t)(lane & 3) * 16;
    const char* Ag = (const char*)A + ((size_t)(row0 + srow) * K) * 2 + sboff;
    const char* Bg = (const char*)Wt + ((size_t)(col0 + srow) * K) * 2 + sboff;
    const size_t rstep = (size_t)16 * K * 2;
    const int woff = w * 2048;
    const int T = K >> 5;

#define STAGE(t, bi) do {                                      \
        size_t kb = (size_t)(t) << 6;                          \
        char* asw = (char*)As + (bi) * 8192 + woff;            \
        char* bsw = (char*)Bs + (bi) * 8192 + woff;            \
        gload16(Ag + kb, asw);                                 \
        gload16(Ag + kb + rstep, asw + 1024);                  \
        gload16(Bg + kb, bsw);                                 \
        gload16(Bg + kb + rstep, bsw + 1024);                  \
    } while (0)

    STAGE(0, 0);
    STAGE(1, 1);
    asm volatile("s_waitcnt vmcnt(4)" ::: "memory");   // tile 0 landed; tile 1 in flight
    __builtin_amdgcn_s_barrier();
    __builtin_amdgcn_sched_barrier(0);

    int bi = 0;
    for (int t = 0; t < T; ++t) {
        if (t + 2 < T) {
            int nb = bi + 2; if (nb >= 3) nb -= 3;
            STAGE(t + 2, nb);                           // prefetch stays in flight
        }
        const char* Ab = (const char*)As + bi * 8192;
        const char* Bb = (const char*)Bs + bi * 8192;
        bf16x8 af[4], bfr[4];
#pragma unroll
        for (int f = 0; f < 4; ++f) {
            af[f] = *(const bf16x8*)(Ab + (size_t)(wr * 64 + f * 16 + l15) * 64 + (l16 << 4));
            bfr[f] = *(const bf16x8*)(Bb + (size_t)(wc * 64 + f * 16 + l15) * 64 + (l16 << 4));
        }
        __builtin_amdgcn_s_setprio(1);
#pragma unroll
        for (int fi = 0; fi < 4; ++fi)
#pragma unroll
            for (int fj = 0; fj < 4; ++fj)
                acc[fi][fj] = __builtin_amdgcn_mfma_f32_16x16x32_bf16(af[fi], bfr[fj], acc[fi][fj], 0, 0, 0);
        __builtin_amdgcn_s_setprio(0);
        if (t + 2 < T) {
            asm volatile("s_waitcnt vmcnt(4)" ::: "memory");   // tile t+1 landed, t+2 in flight
        } else {
            asm volatile("s_waitcnt vmcnt(0)" ::: "memory");   // tail drain
        }
        __builtin_amdgcn_s_barrier();
        __builtin_amdgcn_sched_barrier(0);
        if (++bi >= 3) bi = 0;
    }
#undef STAGE

    const int rb = row0 + wr * 64 + (l16 << 2);
    const int cb = col0 + wc * 64 + l15;
#pragma unroll
    for (int fi = 0; fi < 4; ++fi)
#pragma unroll
        for (int fj = 0; fj < 4; ++fj) {
            int c = cb + fj * 16;
            float bv = bias[c];
#pragma unroll
            for (int rr = 0; rr < 4; ++rr) {
                int r = rb + fi * 16 + rr;
                float v = acc[fi][fj][rr] + bv;
                if (EPI == 1) v = gelu_f(v);
                if (EPI == 2) {
                    v += res[(size_t)r * N + c];
                    ((float*)Cout)[(size_t)r * N + c] = v;
                } else {
                    ((__bf16*)Cout)[(size_t)r * N + c] = (__bf16)v;
                }
            }
        }
}

// ---------------- MFMA flash attention (swapped-QK lane-local softmax) ----------------
// grid (32, 64) remapped; block 256 (4 waves, 16 query-rows each).
__global__ __launch_bounds__(256) void attn_mfma(const u16* __restrict__ QKV,
                                                 const u16* __restrict__ Vt,
                                                 u16* __restrict__ O) {
    __shared__ u16 Ks[2][64 * 64];
    __shared__ u16 Vs[2][64 * 64];
    __shared__ u16 Ps[4][16 * 64];
    const int tid = threadIdx.x, lane = tid & 63, w = tid >> 6;
    // XCD clustering: each XCD owns 8 consecutive bh (its K/V slice = 4MB = L2)
    int hw = blockIdx.x + gridDim.x * blockIdx.y;
    int lg = (hw & 7) * 256 + (hw >> 3);
    const int bh = lg >> 5, b = bh >> 4, h = bh & 15;
    const int q0 = (lg & 31) * 64;
    const int l15 = lane & 15, l16 = lane >> 4;

    const u16* Qp = QKV + (size_t)(b * S_ + q0 + w * 16 + l15) * 3072 + h * 64 + (l16 << 3);
    bf16x8 qf0 = *(const bf16x8*)Qp;
    bf16x8 qf1 = *(const bf16x8*)(Qp + 32);

    f32x4 oacc[4];
#pragma unroll
    for (int i = 0; i < 4; ++i) oacc[i] = (f32x4){0.f, 0.f, 0.f, 0.f};
    // per-lane softmax state for query l15 (replicated over the 4 l16 groups)
    float mold_l = -1e30f, lsum_l = 0.f;

    const int sr = lane >> 3;
    const size_t soff = (size_t)(((lane & 7) ^ sr) << 4);  // pre-swizzled source chunk
    const char* Kg = (const char*)QKV + ((size_t)b * S_ * 3072 + 1024 + h * 64) * 2;
    const char* Vg = (const char*)Vt + (size_t)bh * 64 * S_ * 2;
    char* Pw = (char*)Ps[w];
    const float C2 = 0.18033688011112f;   // 0.125 * log2(e)
    const float THRRAW = 44.0f;

    // hoisted, incremented staging pointers (replaces per-tile 64-bit muls)
    const char* kp0 = Kg + (size_t)(w * 16 + sr) * 6144 + soff;
    const char* kp1 = kp0 + 8 * 6144;
    const char* vp0 = Vg + (size_t)(w * 16 + sr) * 4096 + soff;
    const char* vp1 = vp0 + 8 * 4096;
    const size_t KADV = 64 * 6144;    // bytes per kt step
    const size_t VADV = 128;
    char* ksA = (char*)Ks[0] + w * 2048;
    char* ksB = (char*)Ks[1] + w * 2048;
    char* vsA = (char*)Vs[0] + w * 2048;
    char* vsB = (char*)Vs[1] + w * 2048;

    // stage tile 0 -> buffer A
    gload16(kp0, ksA); gload16(kp1, ksA + 1024);
    gload16(vp0, vsA); gload16(vp1, vsA + 1024);
    kp0 += KADV; kp1 += KADV; vp0 += VADV; vp1 += VADV;
    __syncthreads();

    for (int kt = 0; kt < S_ / 64; ++kt) {
        const int cur = kt & 1;
        if (kt < S_ / 64 - 1) {
            char* kd = cur ? ksA : ksB;
            char* vd = cur ? vsA : vsB;
            gload16(kp0, kd); gload16(kp1, kd + 1024);
            gload16(vp0, vd); gload16(vp1, vd + 1024);
            kp0 += KADV; kp1 += KADV; vp0 += VADV; vp1 += VADV;
        }

        // S^T = K @ Q^T  (per wave: 64 keys x 16 queries; col = query = l15)
        f32x4 sfr[4];
        const char* Kb_ = (const char*)Ks[cur];
        __builtin_amdgcn_s_setprio(1);
#pragma unroll
        for (int cf = 0; cf < 4; ++cf) {
            int r = cf * 16 + l15;
            int x0 = (l16 << 4) ^ ((r & 7) << 4);
            bf16x8 k0v = *(const bf16x8*)(Kb_ + r * 128 + x0);
            bf16x8 k1v = *(const bf16x8*)(Kb_ + r * 128 + (x0 ^ 64));
            f32x4 t = (f32x4){0.f, 0.f, 0.f, 0.f};
            t = __builtin_amdgcn_mfma_f32_16x16x32_bf16(k0v, qf0, t, 0, 0, 0);
            t = __builtin_amdgcn_mfma_f32_16x16x32_bf16(k1v, qf1, t, 0, 0, 0);
            sfr[cf] = t;   // sfr[cf][rr] = S[key = cf*16 + l16*4 + rr][query l15]
        }
        __builtin_amdgcn_s_setprio(0);

        // lane-local max (max3-fusable groups), then 2-step cross-group reduce
        float mx = fmaxf(fmaxf(sfr[0][0], sfr[0][1]), sfr[0][2]);
        mx = fmaxf(fmaxf(mx, sfr[0][3]), sfr[1][0]);
        mx = fmaxf(fmaxf(mx, sfr[1][1]), sfr[1][2]);
        mx = fmaxf(fmaxf(mx, sfr[1][3]), sfr[2][0]);
        mx = fmaxf(fmaxf(mx, sfr[2][1]), sfr[2][2]);
        mx = fmaxf(fmaxf(mx, sfr[2][3]), sfr[3][0]);
        mx = fmaxf(fmaxf(mx, sfr[3][1]), sfr[3][2]);
        mx = fmaxf(mx, sfr[3][3]);
        mx = fmaxf(mx, __shfl_xor(mx, 16, 64));
        mx = fmaxf(mx, __shfl_xor(mx, 32, 64));

        // defer-max: rescale only when this query's max grew past threshold
        bool need = mx > mold_l + THRRAW;
        if (__any(need)) {
            float mnew = fmaxf(mold_l, mx);
            float al = exp2f((mold_l - mnew) * C2);
            lsum_l *= al;
            mold_l = mnew;
#pragma unroll
            for (int rr = 0; rr < 4; ++rr) {
                float alq = __shfl(al, (l16 << 2) + rr, 64);  // stat lives in lane q (0..15)
#pragma unroll
                for (int fj = 0; fj < 4; ++fj) oacc[fj][rr] *= alq;
            }
        }

        // P = exp2(C2*s - C2*m): 16 lane-local values, lane-local sum + 2 shfl
        float nm = -mold_l * C2;
        float pv[4][4];
        float psum = 0.f;
#pragma unroll
        for (int cf = 0; cf < 4; ++cf)
#pragma unroll
            for (int rr = 0; rr < 4; ++rr) {
                float p = exp2f(fmaf(sfr[cf][rr], C2, nm));
                pv[cf][rr] = p;
                psum += p;
            }
        psum += __shfl_xor(psum, 16, 64);
        psum += __shfl_xor(psum, 32, 64);
        lsum_l += psum;

        // P -> LDS: row = query l15, keys cf*16 + l16*4 + rr are consecutive -> b64 writes
        {
            char* Pr = Pw + l15 * 128;
            const int sw = (l15 & 7) << 4;
#pragma unroll
            for (int cf = 0; cf < 4; ++cf) {
                bf16x4 pk = {(__bf16)pv[cf][0], (__bf16)pv[cf][1],
                             (__bf16)pv[cf][2], (__bf16)pv[cf][3]};
                *(bf16x4*)(Pr + ((cf * 32 + l16 * 8) ^ sw)) = pk;
            }
        }

        // O += P @ V
        {
            const char* Vb_ = (const char*)Vs[cur];
            int x0 = (l16 << 4) ^ ((l15 & 7) << 4);
            bf16x8 pf0 = *(const bf16x8*)(Pw + l15 * 128 + x0);
            bf16x8 pf1 = *(const bf16x8*)(Pw + l15 * 128 + (x0 ^ 64));
            __builtin_amdgcn_s_setprio(1);
#pragma unroll
            for (int fj = 0; fj < 4; ++fj) {
                int vr = fj * 16 + l15;
                int y0 = (l16 << 4) ^ ((vr & 7) << 4);
                bf16x8 v0 = *(const bf16x8*)(Vb_ + vr * 128 + y0);
                bf16x8 v1 = *(const bf16x8*)(Vb_ + vr * 128 + (y0 ^ 64));
                oacc[fj] = __builtin_amdgcn_mfma_f32_16x16x32_bf16(pf0, v0, oacc[fj], 0, 0, 0);
                oacc[fj] = __builtin_amdgcn_mfma_f32_16x16x32_bf16(pf1, v1, oacc[fj], 0, 0, 0);
            }
            __builtin_amdgcn_s_setprio(0);
        }
        __syncthreads();   // drains prefetch vmcnt + protects buffer swap
    }

    float inv_l = 1.0f / lsum_l;
    float invq[4];
#pragma unroll
    for (int rr = 0; rr < 4; ++rr) invq[rr] = __shfl(inv_l, (l16 << 2) + rr, 64);
#pragma unroll
    for (int fj = 0; fj < 4; ++fj)
#pragma unroll
        for (int rr = 0; rr < 4; ++rr) {
            int r = b * S_ + q0 + w * 16 + (l16 << 2) + rr;
            ((__bf16*)O)[(size_t)r * D_ + h * 64 + fj * 16 + l15] = (__bf16)(oacc[fj][rr] * invq[rr]);
        }
}

// ---------------- launch ----------------
extern "C" void kernel_launch(void* const* d_in, const int* in_sizes, int n_in,
                              void* d_out, int out_size, void* d_ws, size_t ws_size,
                              hipStream_t stream) {
    const float* x     = (const float*)d_in[0];
    const float* Wq    = (const float*)d_in[1];
    const float* bq    = (const float*)d_in[2];
    const float* Wk    = (const float*)d_in[3];
    const float* bk    = (const float*)d_in[4];
    const float* Wv    = (const float*)d_in[5];
    const float* bv    = (const float*)d_in[6];
    const float* Wo    = (const float*)d_in[7];
    const float* bo    = (const float*)d_in[8];
    const float* ln1_g = (const float*)d_in[9];
    const float* ln1_b = (const float*)d_in[10];
    const float* ln2_g = (const float*)d_in[11];
    const float* ln2_b = (const float*)d_in[12];
    const float* W1    = (const float*)d_in[13];
    const float* b1    = (const float*)d_in[14];
    const float* W2    = (const float*)d_in[15];
    const float* b2    = (const float*)d_in[16];
    float* out = (float*)d_out;

    const size_t MB = 1ull << 20;
    char* ws = (char*)d_ws;
    u16* QKVb = (u16*)(ws + 0 * MB);      // 48MB [8192][3072]
    u16* aout = (u16*)(ws + 48 * MB);     // 16MB [8192][1024]
    u16* mid  = (u16*)(ws + 0 * MB);      // 64MB [8192][4096] (reuses QKVb+aout after out-proj)
    float* x2 = (float*)(ws + 64 * MB);   // 32MB f32
    float* bqkv = (float*)(ws + 64 * MB); // 12KB (dead once x2 is written)
    u16* xn   = (u16*)(ws + 96 * MB);     // 16MB
    u16* Vt   = (u16*)(ws + 96 * MB);     // 16MB (reuses xn after QKV)
    u16* xn2  = (u16*)(ws + 96 * MB);     // 16MB (reuses Vt after attn)
    u16* Wqkvt = (u16*)(ws + 112 * MB);   // 6MB [3072][1024]
    u16* Wot  = Wqkvt + (size_t)3072 * D_;// 2MB
    u16* W1t  = (u16*)(ws + 112 * MB);    // 8MB (reuses Wqkvt+Wot after out-proj)
    u16* W2t  = (u16*)(ws + 120 * MB);    // 8MB

    // weight conversions + bias pack
    wtrans_k<<<dim3(32, 32), 256, 0, stream>>>(Wq, Wqkvt, D_, D_);
    wtrans_k<<<dim3(32, 32), 256, 0, stream>>>(Wk, Wqkvt + (size_t)D_ * D_, D_, D_);
    wtrans_k<<<dim3(32, 32), 256, 0, stream>>>(Wv, Wqkvt + (size_t)2 * D_ * D_, D_, D_);
    wtrans_k<<<dim3(32, 32), 256, 0, stream>>>(Wo, Wot, D_, D_);
    wtrans_k<<<dim3(32, 128), 256, 0, stream>>>(W2, W2t, MLP_, D_);
    pack3_k<<<3, 1024, 0, stream>>>(bq, bk, bv, bqkv);

    // LN1
    ln_bf16_k<<<MROWS, 256, 0, stream>>>(x, ln1_g, ln1_b, xn);
    // fused QKV projection: [8192][3072]
    gemm_bf16<0><<<dim3(24, 64), 256, 0, stream>>>(xn, Wqkvt, bqkv, nullptr, QKVb, MROWS, 3072, D_);
    // V transpose per head
    vtrans_k<<<dim3(32, 64), 256, 0, stream>>>(QKVb, Vt);
    // attention
    attn_mfma<<<dim3(32, 64), 256, 0, stream>>>(QKVb, Vt, aout);
    // out projection + residual -> x2 (f32)
    gemm_bf16<2><<<dim3(8, 64), 256, 0, stream>>>(aout, Wot, bo, x, x2, MROWS, D_, D_);
    // W1 transpose (Wqkvt/Wot now dead), LN2
    wtrans_k<<<dim3(128, 32), 256, 0, stream>>>(W1, W1t, D_, MLP_);
    ln_bf16_k<<<MROWS, 256, 0, stream>>>(x2, ln2_g, ln2_b, xn2);
    // MLP
    gemm_bf16<1><<<dim3(32, 64), 256, 0, stream>>>(xn2, W1t, b1, nullptr, mid, MROWS, MLP_, D_);
    gemm_bf16<2><<<dim3(8, 64), 256, 0, stream>>>(mid, W2t, b2, x2, (void*)out, MROWS, D_, MLP_);
}

// Round 6
// 503.958 us; speedup vs baseline: 8.9631x; 1.0001x over previous
//
#include <hip/hip_runtime.h>
#include <math.h>

#define B_ 4
#define S_ 2048
#define D_ 1024
#define H_ 16
#define MLP_ 4096
#define MROWS 8192

typedef __attribute__((ext_vector_type(4))) float f32x4;
typedef __attribute__((ext_vector_type(16))) float f32x16;
typedef __attribute__((ext_vector_type(8))) __bf16 bf16x8;
typedef __attribute__((ext_vector_type(4))) __bf16 bf16x4;
typedef __attribute__((ext_vector_type(8))) unsigned short us8;
typedef unsigned short u16;
typedef unsigned int u32;

__device__ __forceinline__ void gload16(const void* g, void* l) {
    __builtin_amdgcn_global_load_lds((const __attribute__((address_space(1))) u32*)g,
                                     (__attribute__((address_space(3))) u32*)l, 16, 0, 0);
}

__device__ __forceinline__ float gelu_f(float v) {
    return 0.5f * v * (1.0f + erff(v * 0.70710678118654752f));
}

// ---------------- LayerNorm: f32 in -> bf16 out ----------------
__global__ __launch_bounds__(256) void ln_bf16_k(const float* __restrict__ x,
                                                 const float* __restrict__ g,
                                                 const float* __restrict__ b,
                                                 u16* __restrict__ y) {
    int row = blockIdx.x;
    int tid = threadIdx.x;
    const float* xr = x + (size_t)row * D_;
    f32x4 v = *(const f32x4*)(xr + tid * 4);
    float s = v.x + v.y + v.z + v.w;
    float ss = v.x * v.x + v.y * v.y + v.z * v.z + v.w * v.w;
    for (int off = 32; off > 0; off >>= 1) {
        s += __shfl_down(s, off, 64);
        ss += __shfl_down(ss, off, 64);
    }
    __shared__ float rs[4], rss[4];
    int lane = tid & 63, wid = tid >> 6;
    if (lane == 0) { rs[wid] = s; rss[wid] = ss; }
    __syncthreads();
    s = rs[0] + rs[1] + rs[2] + rs[3];
    ss = rss[0] + rss[1] + rss[2] + rss[3];
    float mu = s * (1.0f / D_);
    float var = ss * (1.0f / D_) - mu * mu;
    float inv = rsqrtf(var + 1e-6f);
    f32x4 gg = *(const f32x4*)(g + tid * 4);
    f32x4 bb = *(const f32x4*)(b + tid * 4);
    bf16x4 o = {(__bf16)((v.x - mu) * inv * gg.x + bb.x),
                (__bf16)((v.y - mu) * inv * gg.y + bb.y),
                (__bf16)((v.z - mu) * inv * gg.z + bb.z),
                (__bf16)((v.w - mu) * inv * gg.w + bb.w)};
    *(bf16x4*)(y + (size_t)row * D_ + tid * 4) = o;
}

// ---------------- bias pack: bqkv = [bq|bk|bv] ----------------
__global__ void pack3_k(const float* __restrict__ a, const float* __restrict__ b,
                        const float* __restrict__ c, float* __restrict__ o) {
    const float* s = blockIdx.x == 0 ? a : (blockIdx.x == 1 ? b : c);
    o[blockIdx.x * 1024 + threadIdx.x] = s[threadIdx.x];
}

// ---------------- weight transpose+convert: W[K,N] f32 -> Wt[N,K] bf16 ----------------
__global__ __launch_bounds__(256) void wtrans_k(const float* __restrict__ W,
                                                u16* __restrict__ Wt, int K, int N) {
    __shared__ float T[32][33];
    int tid = threadIdx.x;
    int k0 = blockIdx.y * 32, n0 = blockIdx.x * 32;
    int r = tid >> 3, c4 = (tid & 7) * 4;
    f32x4 v = *(const f32x4*)&W[(size_t)(k0 + r) * N + n0 + c4];
    T[r][c4 + 0] = v.x; T[r][c4 + 1] = v.y; T[r][c4 + 2] = v.z; T[r][c4 + 3] = v.w;
    __syncthreads();
    int n = tid >> 3, kk = (tid & 7) * 4;
    bf16x4 o = {(__bf16)T[kk + 0][n], (__bf16)T[kk + 1][n],
                (__bf16)T[kk + 2][n], (__bf16)T[kk + 3][n]};
    *(bf16x4*)&Wt[(size_t)(n0 + n) * K + k0 + kk] = o;
}

// ---------------- V transpose: QKV bf16 [B*S,3072] (V cols) -> Vt bf16 [B*H*64][S] ----------------
__global__ __launch_bounds__(256) void vtrans_k(const u16* __restrict__ QKV,
                                                u16* __restrict__ Vt) {
    __shared__ u16 T[64][80];
    int tid = threadIdx.x;
    int s0 = blockIdx.x * 64;
    int bh = blockIdx.y, b = bh >> 4, h = bh & 15;
    int r = tid >> 2, c0 = (tid & 3) * 16;
    const u16* src = QKV + (size_t)(b * S_ + s0 + r) * 3072 + 2048 + h * 64 + c0;
    us8 v0 = *(const us8*)src;
    us8 v1 = *(const us8*)(src + 8);
    *(us8*)&T[r][c0] = v0;
    *(us8*)&T[r][c0 + 8] = v1;
    __syncthreads();
    int dh = tid >> 2, s8 = (tid & 3) * 16;
    us8 o0, o1;
#pragma unroll
    for (int i = 0; i < 8; ++i) { o0[i] = T[s8 + i][dh]; o1[i] = T[s8 + 8 + i][dh]; }
    u16* dst = Vt + (size_t)(bh * 64 + dh) * S_ + s0 + s8;
    *(us8*)dst = o0;
    *(us8*)(dst + 8) = o1;
}

// ---------------- bf16 MFMA GEMM, depth-2 prefetch pipeline ----------------
// C[M,N] = A[M,K] @ Wt[N,K]^T (+epilogue)
// EPI: 0 = +bias -> bf16 ; 1 = gelu(+bias) -> bf16 ; 2 = +bias +res -> f32
template <int EPI>
__global__ __launch_bounds__(256) void gemm_bf16(const u16* __restrict__ A,
                                                 const u16* __restrict__ Wt,
                                                 const float* __restrict__ bias,
                                                 const float* __restrict__ res,
                                                 void* __restrict__ Cout,
                                                 int M, int N, int K) {
    __shared__ u16 As[3][128 * 32];   // 3-deep rotation, 8KB each
    __shared__ u16 Bs[3][128 * 32];
    const int tid = threadIdx.x;
    const int lane = tid & 63;
    const int w = tid >> 6;
    // XCD-chunked bijective remap (nwg % 8 == 0 for all our grids)
    const int nwg = gridDim.x * gridDim.y;
    int hw = blockIdx.x + gridDim.x * blockIdx.y;
    int lg = (hw & 7) * (nwg >> 3) + (hw >> 3);
    const int row0 = (lg / gridDim.x) * 128;
    const int col0 = (lg % gridDim.x) * 128;
    const int l15 = lane & 15, l16 = lane >> 4;
    const int wr = w >> 1, wc = w & 1;

    f32x4 acc[4][4];
#pragma unroll
    for (int i = 0; i < 4; ++i)
#pragma unroll
        for (int j = 0; j < 4; ++j) acc[i][j] = (f32x4){0.f, 0.f, 0.f, 0.f};

    const int srow = w * 32 + (lane >> 2);
    const size_t sboff = (size_t)(lane & 3) * 16;
    const char* Ag = (const char*)A + ((size_t)(row0 + srow) * K) * 2 + sboff;
    const char* Bg = (const char*)Wt + ((size_t)(col0 + srow) * K) * 2 + sboff;
    const size_t rstep = (size_t)16 * K * 2;
    const int woff = w * 2048;
    const int T = K >> 5;

#define STAGE(t, bi) do {                                      \
        size_t kb = (size_t)(t) << 6;                          \
        char* asw = (char*)As + (bi) * 8192 + woff;            \
        char* bsw = (char*)Bs + (bi) * 8192 + woff;            \
        gload16(Ag + kb, asw);                                 \
        gload16(Ag + kb + rstep, asw + 1024);                  \
        gload16(Bg + kb, bsw);                                 \
        gload16(Bg + kb + rstep, bsw + 1024);                  \
    } while (0)

    STAGE(0, 0);
    STAGE(1, 1);
    asm volatile("s_waitcnt vmcnt(4)" ::: "memory");   // tile 0 landed; tile 1 in flight
    __builtin_amdgcn_s_barrier();
    __builtin_amdgcn_sched_barrier(0);

    int bi = 0;
    for (int t = 0; t < T; ++t) {
        if (t + 2 < T) {
            int nb = bi + 2; if (nb >= 3) nb -= 3;
            STAGE(t + 2, nb);                           // prefetch stays in flight
        }
        const char* Ab = (const char*)As + bi * 8192;
        const char* Bb = (const char*)Bs + bi * 8192;
        bf16x8 af[4], bfr[4];
#pragma unroll
        for (int f = 0; f < 4; ++f) {
            af[f] = *(const bf16x8*)(Ab + (size_t)(wr * 64 + f * 16 + l15) * 64 + (l16 << 4));
            bfr[f] = *(const bf16x8*)(Bb + (size_t)(wc * 64 + f * 16 + l15) * 64 + (l16 << 4));
        }
        __builtin_amdgcn_s_setprio(1);
#pragma unroll
        for (int fi = 0; fi < 4; ++fi)
#pragma unroll
            for (int fj = 0; fj < 4; ++fj)
                acc[fi][fj] = __builtin_amdgcn_mfma_f32_16x16x32_bf16(af[fi], bfr[fj], acc[fi][fj], 0, 0, 0);
        __builtin_amdgcn_s_setprio(0);
        if (t + 2 < T) {
            asm volatile("s_waitcnt vmcnt(4)" ::: "memory");   // tile t+1 landed, t+2 in flight
        } else {
            asm volatile("s_waitcnt vmcnt(0)" ::: "memory");   // tail drain
        }
        __builtin_amdgcn_s_barrier();
        __builtin_amdgcn_sched_barrier(0);
        if (++bi >= 3) bi = 0;
    }
#undef STAGE

    const int rb = row0 + wr * 64 + (l16 << 2);
    const int cb = col0 + wc * 64 + l15;
#pragma unroll
    for (int fi = 0; fi < 4; ++fi)
#pragma unroll
        for (int fj = 0; fj < 4; ++fj) {
            int c = cb + fj * 16;
            float bv = bias[c];
#pragma unroll
            for (int rr = 0; rr < 4; ++rr) {
                int r = rb + fi * 16 + rr;
                float v = acc[fi][fj][rr] + bv;
                if (EPI == 1) v = gelu_f(v);
                if (EPI == 2) {
                    v += res[(size_t)r * N + c];
                    ((float*)Cout)[(size_t)r * N + c] = v;
                } else {
                    ((__bf16*)Cout)[(size_t)r * N + c] = (__bf16)v;
                }
            }
        }
}

// ---------------- MFMA flash attention: 32 queries/wave, 32x32x16 MFMA ----------------
// grid (16, 64) remapped; block 256 (4 waves, 32 query-rows each; 128 q / block).
// Swapped QK^T (col=query) and O^T = V^T @ P^T (col=query) -> softmax fully lane-local.
__global__ __launch_bounds__(256) void attn_mfma(const u16* __restrict__ QKV,
                                                 const u16* __restrict__ Vt,
                                                 u16* __restrict__ O) {
    __shared__ u16 Ks[2][64 * 64];
    __shared__ u16 Vs[2][64 * 64];
    __shared__ u16 Ps[4][32 * 64];
    const int tid = threadIdx.x, lane = tid & 63, w = tid >> 6;
    // XCD clustering: each XCD owns 8 consecutive bh
    int hw = blockIdx.x + gridDim.x * blockIdx.y;
    int lg = (hw & 7) * 128 + (hw >> 3);
    const int bh = lg >> 4, b = bh >> 4, h = bh & 15;
    const int q0 = (lg & 15) * 128;
    const int l31 = lane & 31, lh = lane >> 5;

    // Q B-frags: qf[ds] = Q[q][ds*16 + lh*8 .. +8], q = q0 + w*32 + l31
    const u16* Qp = QKV + (size_t)(b * S_ + q0 + w * 32 + l31) * 3072 + h * 64 + lh * 8;
    bf16x8 qf[4];
    qf[0] = *(const bf16x8*)(Qp);
    qf[1] = *(const bf16x8*)(Qp + 16);
    qf[2] = *(const bf16x8*)(Qp + 32);
    qf[3] = *(const bf16x8*)(Qp + 48);

    f32x16 oacc[2];
#pragma unroll
    for (int i = 0; i < 16; ++i) { oacc[0][i] = 0.f; oacc[1][i] = 0.f; }
    float mold = -1e30f, lsum = 0.f;

    const int sr = lane >> 3;
    const size_t soff = (size_t)(((lane & 7) ^ sr) << 4);  // pre-swizzled source chunk
    const char* Kg = (const char*)QKV + ((size_t)b * S_ * 3072 + 1024 + h * 64) * 2;
    const char* Vg = (const char*)Vt + (size_t)bh * 64 * S_ * 2;
    char* Pw = (char*)Ps[w];
    const int sw = (l31 & 7) << 4;
    const float C2 = 0.18033688011112f;   // 0.125 * log2(e)
    const float THRRAW = 44.0f;

    // staging pointers (pointer-increment, no per-tile 64-bit muls)
    const char* kp0 = Kg + (size_t)(w * 16 + sr) * 6144 + soff;
    const char* kp1 = kp0 + 8 * 6144;
    const char* vp0 = Vg + (size_t)(w * 16 + sr) * 4096 + soff;
    const char* vp1 = vp0 + 8 * 4096;
    const size_t KADV = 64 * 6144;
    const size_t VADV = 128;
    char* ksA = (char*)Ks[0] + w * 2048;
    char* ksB = (char*)Ks[1] + w * 2048;
    char* vsA = (char*)Vs[0] + w * 2048;
    char* vsB = (char*)Vs[1] + w * 2048;

    gload16(kp0, ksA); gload16(kp1, ksA + 1024);
    gload16(vp0, vsA); gload16(vp1, vsA + 1024);
    kp0 += KADV; kp1 += KADV; vp0 += VADV; vp1 += VADV;
    __syncthreads();

    for (int kt = 0; kt < S_ / 64; ++kt) {
        const int cur = kt & 1;
        if (kt < S_ / 64 - 1) {
            char* kd = cur ? ksA : ksB;
            char* vd = cur ? vsA : vsB;
            gload16(kp0, kd); gload16(kp1, kd + 1024);
            gload16(vp0, vd); gload16(vp1, vd + 1024);
            kp0 += KADV; kp1 += KADV; vp0 += VADV; vp1 += VADV;
        }

        // S^T = K @ Q^T : two 32-key halves, K-dim 64 in 4 steps of 16
        const char* Kb_ = (const char*)Ks[cur];
        f32x16 sfr[2];
        __builtin_amdgcn_s_setprio(1);
#pragma unroll
        for (int kh = 0; kh < 2; ++kh) {
            int r = kh * 32 + l31;
            int rsw = (r & 7) << 4;
            const char* Kr = Kb_ + r * 128;
            f32x16 t;
#pragma unroll
            for (int i = 0; i < 16; ++i) t[i] = 0.f;
#pragma unroll
            for (int ds = 0; ds < 4; ++ds) {
                bf16x8 kf = *(const bf16x8*)(Kr + ((((ds * 2 + lh) << 4)) ^ rsw));
                t = __builtin_amdgcn_mfma_f32_32x32x16_bf16(kf, qf[ds], t, 0, 0, 0);
            }
            sfr[kh] = t;
        }
        __builtin_amdgcn_s_setprio(0);
        // sfr[kh][r]: score of key (kh*32 + (r&3)+8*(r>>2)+4*lh) for query l31 (this lane)

        // lane-local 32-max + one cross-half reduce
        float mx = fmaxf(sfr[0][0], sfr[1][0]);
#pragma unroll
        for (int i = 1; i < 16; ++i) mx = fmaxf(mx, fmaxf(sfr[0][i], sfr[1][i]));
        mx = fmaxf(mx, __shfl_xor(mx, 32, 64));

        // defer-max rescale (lane-local: O^T col = this lane's query)
        bool need = mx > mold + THRRAW;
        if (__any(need)) {
            float mnew = fmaxf(mold, mx);
            float al = exp2f((mold - mnew) * C2);
            lsum *= al;
            mold = mnew;
#pragma unroll
            for (int i = 0; i < 16; ++i) { oacc[0][i] *= al; oacc[1][i] *= al; }
        }

        // P = exp2(C2*s - C2*m), lane-local sum + one cross-half reduce
        float nm = -mold * C2;
        float pv0[16], pv1[16];
        float psum = 0.f;
#pragma unroll
        for (int i = 0; i < 16; ++i) {
            pv0[i] = exp2f(fmaf(sfr[0][i], C2, nm));
            pv1[i] = exp2f(fmaf(sfr[1][i], C2, nm));
            psum += pv0[i] + pv1[i];
        }
        psum += __shfl_xor(psum, 32, 64);
        lsum += psum;

        // P -> LDS: row = query l31; reg groups of 4 = consecutive keys -> b64 writes
        {
            char* Pr = Pw + l31 * 128;
#pragma unroll
            for (int t4 = 0; t4 < 4; ++t4) {
                int kb0 = (t4 * 8 + lh * 4) * 2;
                bf16x4 pa = {(__bf16)pv0[t4 * 4], (__bf16)pv0[t4 * 4 + 1],
                             (__bf16)pv0[t4 * 4 + 2], (__bf16)pv0[t4 * 4 + 3]};
                bf16x4 pb = {(__bf16)pv1[t4 * 4], (__bf16)pv1[t4 * 4 + 1],
                             (__bf16)pv1[t4 * 4 + 2], (__bf16)pv1[t4 * 4 + 3]};
                *(bf16x4*)(Pr + (kb0 ^ sw)) = pa;
                *(bf16x4*)(Pr + ((kb0 + 64) ^ sw)) = pb;
            }
        }

        // O^T += V^T @ P^T  (A = Vt rows = d, B = P^T cols = q)
        {
            const char* Vb_ = (const char*)Vs[cur];
            const char* Pr = Pw + l31 * 128;
            bf16x8 pf[4];
#pragma unroll
            for (int ks = 0; ks < 4; ++ks)
                pf[ks] = *(const bf16x8*)(Pr + ((((ks * 2 + lh) << 4)) ^ sw));
            __builtin_amdgcn_s_setprio(1);
#pragma unroll
            for (int dh = 0; dh < 2; ++dh) {
                int r = dh * 32 + l31;
                int rsw = (r & 7) << 4;
                const char* Vr = Vb_ + r * 128;
#pragma unroll
                for (int ks = 0; ks < 4; ++ks) {
                    bf16x8 vf = *(const bf16x8*)(Vr + ((((ks * 2 + lh) << 4)) ^ rsw));
                    oacc[dh] = __builtin_amdgcn_mfma_f32_32x32x16_bf16(vf, pf[ks], oacc[dh], 0, 0, 0);
                }
            }
            __builtin_amdgcn_s_setprio(0);
        }
        __syncthreads();   // drains prefetch vmcnt + protects buffer swap
    }

    // epilogue: O^T col = query (lane-local stats); reg groups of 4 = consecutive d
    float invl = 1.0f / lsum;
    char* Og = (char*)O + ((size_t)(b * S_ + q0 + w * 32 + l31) * 1024 + h * 64) * 2;
#pragma unroll
    for (int dh = 0; dh < 2; ++dh)
#pragma unroll
        for (int t4 = 0; t4 < 4; ++t4) {
            int db = dh * 32 + t4 * 8 + lh * 4;
            bf16x4 ov = {(__bf16)(oacc[dh][t4 * 4] * invl),
                         (__bf16)(oacc[dh][t4 * 4 + 1] * invl),
                         (__bf16)(oacc[dh][t4 * 4 + 2] * invl),
                         (__bf16)(oacc[dh][t4 * 4 + 3] * invl)};
            *(bf16x4*)(Og + db * 2) = ov;
        }
}

// ---------------- launch ----------------
extern "C" void kernel_launch(void* const* d_in, const int* in_sizes, int n_in,
                              void* d_out, int out_size, void* d_ws, size_t ws_size,
                              hipStream_t stream) {
    const float* x     = (const float*)d_in[0];
    const float* Wq    = (const float*)d_in[1];
    const float* bq    = (const float*)d_in[2];
    const float* Wk    = (const float*)d_in[3];
    const float* bk    = (const float*)d_in[4];
    const float* Wv    = (const float*)d_in[5];
    const float* bv    = (const float*)d_in[6];
    const float* Wo    = (const float*)d_in[7];
    const float* bo    = (const float*)d_in[8];
    const float* ln1_g = (const float*)d_in[9];
    const float* ln1_b = (const float*)d_in[10];
    const float* ln2_g = (const float*)d_in[11];
    const float* ln2_b = (const float*)d_in[12];
    const float* W1    = (const float*)d_in[13];
    const float* b1    = (const float*)d_in[14];
    const float* W2    = (const float*)d_in[15];
    const float* b2    = (const float*)d_in[16];
    float* out = (float*)d_out;

    const size_t MB = 1ull << 20;
    char* ws = (char*)d_ws;
    u16* QKVb = (u16*)(ws + 0 * MB);      // 48MB [8192][3072]
    u16* aout = (u16*)(ws + 48 * MB);     // 16MB [8192][1024]
    u16* mid  = (u16*)(ws + 0 * MB);      // 64MB [8192][4096] (reuses QKVb+aout after out-proj)
    float* x2 = (float*)(ws + 64 * MB);   // 32MB f32
    float* bqkv = (float*)(ws + 64 * MB); // 12KB (dead once x2 is written)
    u16* xn   = (u16*)(ws + 96 * MB);     // 16MB
    u16* Vt   = (u16*)(ws + 96 * MB);     // 16MB (reuses xn after QKV)
    u16* xn2  = (u16*)(ws + 96 * MB);     // 16MB (reuses Vt after attn)
    u16* Wqkvt = (u16*)(ws + 112 * MB);   // 6MB [3072][1024]
    u16* Wot  = Wqkvt + (size_t)3072 * D_;// 2MB
    u16* W1t  = (u16*)(ws + 112 * MB);    // 8MB (reuses Wqkvt+Wot after out-proj)
    u16* W2t  = (u16*)(ws + 120 * MB);    // 8MB

    // weight conversions + bias pack
    wtrans_k<<<dim3(32, 32), 256, 0, stream>>>(Wq, Wqkvt, D_, D_);
    wtrans_k<<<dim3(32, 32), 256, 0, stream>>>(Wk, Wqkvt + (size_t)D_ * D_, D_, D_);
    wtrans_k<<<dim3(32, 32), 256, 0, stream>>>(Wv, Wqkvt + (size_t)2 * D_ * D_, D_, D_);
    wtrans_k<<<dim3(32, 32), 256, 0, stream>>>(Wo, Wot, D_, D_);
    wtrans_k<<<dim3(32, 128), 256, 0, stream>>>(W2, W2t, MLP_, D_);
    pack3_k<<<3, 1024, 0, stream>>>(bq, bk, bv, bqkv);

    // LN1
    ln_bf16_k<<<MROWS, 256, 0, stream>>>(x, ln1_g, ln1_b, xn);
    // fused QKV projection: [8192][3072]
    gemm_bf16<0><<<dim3(24, 64), 256, 0, stream>>>(xn, Wqkvt, bqkv, nullptr, QKVb, MROWS, 3072, D_);
    // V transpose per head
    vtrans_k<<<dim3(32, 64), 256, 0, stream>>>(QKVb, Vt);
    // attention (128 queries/block)
    attn_mfma<<<dim3(16, 64), 256, 0, stream>>>(QKVb, Vt, aout);
    // out projection + residual -> x2 (f32)
    gemm_bf16<2><<<dim3(8, 64), 256, 0, stream>>>(aout, Wot, bo, x, x2, MROWS, D_, D_);
    // W1 transpose (Wqkvt/Wot now dead), LN2
    wtrans_k<<<dim3(128, 32), 256, 0, stream>>>(W1, W1t, D_, MLP_);
    ln_bf16_k<<<MROWS, 256, 0, stream>>>(x2, ln2_g, ln2_b, xn2);
    // MLP
    gemm_bf16<1><<<dim3(32, 64), 256, 0, stream>>>(xn2, W1t, b1, nullptr, mid, MROWS, MLP_, D_);
    gemm_bf16<2><<<dim3(8, 64), 256, 0, stream>>>(mid, W2t, b2, x2, (void*)out, MROWS, D_, MLP_);
}

// Round 7
// 465.096 us; speedup vs baseline: 9.7120x; 1.0836x over previous
//
#include <hip/hip_runtime.h>
#include <math.h>

#define B_ 4
#define S_ 2048
#define D_ 1024
#define H_ 16
#define MLP_ 4096
#define MROWS 8192

typedef __attribute__((ext_vector_type(4))) float f32x4;
typedef __attribute__((ext_vector_type(16))) float f32x16;
typedef __attribute__((ext_vector_type(8))) __bf16 bf16x8;
typedef __attribute__((ext_vector_type(4))) __bf16 bf16x4;
typedef __attribute__((ext_vector_type(8))) unsigned short us8;
typedef unsigned short u16;
typedef unsigned int u32;

__device__ __forceinline__ void gload16(const void* g, void* l) {
    __builtin_amdgcn_global_load_lds((const __attribute__((address_space(1))) u32*)g,
                                     (__attribute__((address_space(3))) u32*)l, 16, 0, 0);
}

__device__ __forceinline__ float gelu_f(float v) {
    return 0.5f * v * (1.0f + erff(v * 0.70710678118654752f));
}

// ---------------- LayerNorm: f32 in -> bf16 out ----------------
__global__ __launch_bounds__(256) void ln_bf16_k(const float* __restrict__ x,
                                                 const float* __restrict__ g,
                                                 const float* __restrict__ b,
                                                 u16* __restrict__ y) {
    int row = blockIdx.x;
    int tid = threadIdx.x;
    const float* xr = x + (size_t)row * D_;
    f32x4 v = *(const f32x4*)(xr + tid * 4);
    float s = v.x + v.y + v.z + v.w;
    float ss = v.x * v.x + v.y * v.y + v.z * v.z + v.w * v.w;
    for (int off = 32; off > 0; off >>= 1) {
        s += __shfl_down(s, off, 64);
        ss += __shfl_down(ss, off, 64);
    }
    __shared__ float rs[4], rss[4];
    int lane = tid & 63, wid = tid >> 6;
    if (lane == 0) { rs[wid] = s; rss[wid] = ss; }
    __syncthreads();
    s = rs[0] + rs[1] + rs[2] + rs[3];
    ss = rss[0] + rss[1] + rss[2] + rss[3];
    float mu = s * (1.0f / D_);
    float var = ss * (1.0f / D_) - mu * mu;
    float inv = rsqrtf(var + 1e-6f);
    f32x4 gg = *(const f32x4*)(g + tid * 4);
    f32x4 bb = *(const f32x4*)(b + tid * 4);
    bf16x4 o = {(__bf16)((v.x - mu) * inv * gg.x + bb.x),
                (__bf16)((v.y - mu) * inv * gg.y + bb.y),
                (__bf16)((v.z - mu) * inv * gg.z + bb.z),
                (__bf16)((v.w - mu) * inv * gg.w + bb.w)};
    *(bf16x4*)(y + (size_t)row * D_ + tid * 4) = o;
}

// ---------------- bias pack: bqkv = [bq|bk|bv] ----------------
__global__ void pack3_k(const float* __restrict__ a, const float* __restrict__ b,
                        const float* __restrict__ c, float* __restrict__ o) {
    const float* s = blockIdx.x == 0 ? a : (blockIdx.x == 1 ? b : c);
    o[blockIdx.x * 1024 + threadIdx.x] = s[threadIdx.x];
}

// ---------------- weight transpose+convert: W[K,N] f32 -> Wt[N,K] bf16 ----------------
__global__ __launch_bounds__(256) void wtrans_k(const float* __restrict__ W,
                                                u16* __restrict__ Wt, int K, int N) {
    __shared__ float T[32][33];
    int tid = threadIdx.x;
    int k0 = blockIdx.y * 32, n0 = blockIdx.x * 32;
    int r = tid >> 3, c4 = (tid & 7) * 4;
    f32x4 v = *(const f32x4*)&W[(size_t)(k0 + r) * N + n0 + c4];
    T[r][c4 + 0] = v.x; T[r][c4 + 1] = v.y; T[r][c4 + 2] = v.z; T[r][c4 + 3] = v.w;
    __syncthreads();
    int n = tid >> 3, kk = (tid & 7) * 4;
    bf16x4 o = {(__bf16)T[kk + 0][n], (__bf16)T[kk + 1][n],
                (__bf16)T[kk + 2][n], (__bf16)T[kk + 3][n]};
    *(bf16x4*)&Wt[(size_t)(n0 + n) * K + k0 + kk] = o;
}

// ---------------- V transpose (sigma-permuted): QKV V-cols -> Vt [B*H*64][S] ----------------
// Column s within each 64-key tile stores key sigma(s) so that the attention
// P fragment equals the QK^T C-layout register order (zero cross-lane traffic).
__device__ __forceinline__ int sigma_perm(int s) {
    return (s & 48) | (s & 3) | (((s >> 2) & 1) << 3) | (((s >> 3) & 1) << 2);
}
__global__ __launch_bounds__(256) void vtrans_k(const u16* __restrict__ QKV,
                                                u16* __restrict__ Vt) {
    __shared__ u16 T[64][80];
    int tid = threadIdx.x;
    int s0 = blockIdx.x * 64;
    int bh = blockIdx.y, b = bh >> 4, h = bh & 15;
    int r = tid >> 2, c0 = (tid & 3) * 16;
    const u16* src = QKV + (size_t)(b * S_ + s0 + r) * 3072 + 2048 + h * 64 + c0;
    us8 v0 = *(const us8*)src;
    us8 v1 = *(const us8*)(src + 8);
    *(us8*)&T[r][c0] = v0;
    *(us8*)&T[r][c0 + 8] = v1;
    __syncthreads();
    int dh = tid >> 2, s8 = (tid & 3) * 16;
    us8 o0, o1;
#pragma unroll
    for (int i = 0; i < 8; ++i) {
        o0[i] = T[sigma_perm(s8 + i)][dh];
        o1[i] = T[sigma_perm(s8 + 8 + i)][dh];
    }
    u16* dst = Vt + (size_t)(bh * 64 + dh) * S_ + s0 + s8;
    *(us8*)dst = o0;
    *(us8*)(dst + 8) = o1;
}

// ---------------- bf16 MFMA GEMM, depth-2 prefetch pipeline ----------------
// C[M,N] = A[M,K] @ Wt[N,K]^T (+epilogue)
// EPI: 0 = +bias -> bf16 ; 1 = gelu(+bias) -> bf16 ; 2 = +bias +res -> f32
template <int EPI>
__global__ __launch_bounds__(256) void gemm_bf16(const u16* __restrict__ A,
                                                 const u16* __restrict__ Wt,
                                                 const float* __restrict__ bias,
                                                 const float* __restrict__ res,
                                                 void* __restrict__ Cout,
                                                 int M, int N, int K) {
    __shared__ u16 As[3][128 * 32];   // 3-deep rotation, 8KB each
    __shared__ u16 Bs[3][128 * 32];
    const int tid = threadIdx.x;
    const int lane = tid & 63;
    const int w = tid >> 6;
    // XCD-chunked bijective remap (nwg % 8 == 0 for all our grids)
    const int nwg = gridDim.x * gridDim.y;
    int hw = blockIdx.x + gridDim.x * blockIdx.y;
    int lg = (hw & 7) * (nwg >> 3) + (hw >> 3);
    const int row0 = (lg / gridDim.x) * 128;
    const int col0 = (lg % gridDim.x) * 128;
    const int l15 = lane & 15, l16 = lane >> 4;
    const int wr = w >> 1, wc = w & 1;

    f32x4 acc[4][4];
#pragma unroll
    for (int i = 0; i < 4; ++i)
#pragma unroll
        for (int j = 0; j < 4; ++j) acc[i][j] = (f32x4){0.f, 0.f, 0.f, 0.f};

    const int srow = w * 32 + (lane >> 2);
    const size_t sboff = (size_t)(lane & 3) * 16;
    const char* Ag = (const char*)A + ((size_t)(row0 + srow) * K) * 2 + sboff;
    const char* Bg = (const char*)Wt + ((size_t)(col0 + srow) * K) * 2 + sboff;
    const size_t rstep = (size_t)16 * K * 2;
    const int woff = w * 2048;
    const int T = K >> 5;

#define STAGE(t, bi) do {                                      \
        size_t kb = (size_t)(t) << 6;                          \
        char* asw = (char*)As + (bi) * 8192 + woff;            \
        char* bsw = (char*)Bs + (bi) * 8192 + woff;            \
        gload16(Ag + kb, asw);                                 \
        gload16(Ag + kb + rstep, asw + 1024);                  \
        gload16(Bg + kb, bsw);                                 \
        gload16(Bg + kb + rstep, bsw + 1024);                  \
    } while (0)

    STAGE(0, 0);
    STAGE(1, 1);
    asm volatile("s_waitcnt vmcnt(4)" ::: "memory");   // tile 0 landed; tile 1 in flight
    __builtin_amdgcn_s_barrier();
    __builtin_amdgcn_sched_barrier(0);

    int bi = 0;
    for (int t = 0; t < T; ++t) {
        if (t + 2 < T) {
            int nb = bi + 2; if (nb >= 3) nb -= 3;
            STAGE(t + 2, nb);                           // prefetch stays in flight
        }
        const char* Ab = (const char*)As + bi * 8192;
        const char* Bb = (const char*)Bs + bi * 8192;
        bf16x8 af[4], bfr[4];
#pragma unroll
        for (int f = 0; f < 4; ++f) {
            af[f] = *(const bf16x8*)(Ab + (size_t)(wr * 64 + f * 16 + l15) * 64 + (l16 << 4));
            bfr[f] = *(const bf16x8*)(Bb + (size_t)(wc * 64 + f * 16 + l15) * 64 + (l16 << 4));
        }
        __builtin_amdgcn_s_setprio(1);
#pragma unroll
        for (int fi = 0; fi < 4; ++fi)
#pragma unroll
            for (int fj = 0; fj < 4; ++fj)
                acc[fi][fj] = __builtin_amdgcn_mfma_f32_16x16x32_bf16(af[fi], bfr[fj], acc[fi][fj], 0, 0, 0);
        __builtin_amdgcn_s_setprio(0);
        if (t + 2 < T) {
            asm volatile("s_waitcnt vmcnt(4)" ::: "memory");   // tile t+1 landed, t+2 in flight
        } else {
            asm volatile("s_waitcnt vmcnt(0)" ::: "memory");   // tail drain
        }
        __builtin_amdgcn_s_barrier();
        __builtin_amdgcn_sched_barrier(0);
        if (++bi >= 3) bi = 0;
    }
#undef STAGE

    const int rb = row0 + wr * 64 + (l16 << 2);
    const int cb = col0 + wc * 64 + l15;
#pragma unroll
    for (int fi = 0; fi < 4; ++fi)
#pragma unroll
        for (int fj = 0; fj < 4; ++fj) {
            int c = cb + fj * 16;
            float bv = bias[c];
#pragma unroll
            for (int rr = 0; rr < 4; ++rr) {
                int r = rb + fi * 16 + rr;
                float v = acc[fi][fj][rr] + bv;
                if (EPI == 1) v = gelu_f(v);
                if (EPI == 2) {
                    v += res[(size_t)r * N + c];
                    ((float*)Cout)[(size_t)r * N + c] = v;
                } else {
                    ((__bf16*)Cout)[(size_t)r * N + c] = (__bf16)v;
                }
            }
        }
}

// ---------------- MFMA flash attention: 32 q/wave, 32x32x16, in-register P ----------------
// grid (16, 64) remapped; block 256 (4 waves, 32 query-rows each; 128 q / block).
// Swapped QK^T (col=query); V columns sigma-permuted so P regs feed PV directly.
__global__ __launch_bounds__(256) void attn_mfma(const u16* __restrict__ QKV,
                                                 const u16* __restrict__ Vt,
                                                 u16* __restrict__ O) {
    __shared__ u16 Ks[2][64 * 64];
    __shared__ u16 Vs[2][64 * 64];
    const int tid = threadIdx.x, lane = tid & 63, w = tid >> 6;
    // XCD clustering: each XCD owns 8 consecutive bh
    int hw = blockIdx.x + gridDim.x * blockIdx.y;
    int lg = (hw & 7) * 128 + (hw >> 3);
    const int bh = lg >> 4, b = bh >> 4, h = bh & 15;
    const int q0 = (lg & 15) * 128;
    const int l31 = lane & 31, lh = lane >> 5;

    // Q B-frags: qf[ds] = Q[q][ds*16 + lh*8 .. +8], q = q0 + w*32 + l31
    const u16* Qp = QKV + (size_t)(b * S_ + q0 + w * 32 + l31) * 3072 + h * 64 + lh * 8;
    bf16x8 qf[4];
    qf[0] = *(const bf16x8*)(Qp);
    qf[1] = *(const bf16x8*)(Qp + 16);
    qf[2] = *(const bf16x8*)(Qp + 32);
    qf[3] = *(const bf16x8*)(Qp + 48);

    f32x16 oacc[2];
#pragma unroll
    for (int i = 0; i < 16; ++i) { oacc[0][i] = 0.f; oacc[1][i] = 0.f; }
    float mold = -1e30f, lsum = 0.f;

    const int sr = lane >> 3;
    const size_t soff = (size_t)(((lane & 7) ^ sr) << 4);  // pre-swizzled source chunk
    const char* Kg = (const char*)QKV + ((size_t)b * S_ * 3072 + 1024 + h * 64) * 2;
    const char* Vg = (const char*)Vt + (size_t)bh * 64 * S_ * 2;
    const float C2 = 0.18033688011112f;   // 0.125 * log2(e)
    const float THRRAW = 44.0f;

    // staging pointers (pointer-increment, no per-tile 64-bit muls)
    const char* kp0 = Kg + (size_t)(w * 16 + sr) * 6144 + soff;
    const char* kp1 = kp0 + 8 * 6144;
    const char* vp0 = Vg + (size_t)(w * 16 + sr) * 4096 + soff;
    const char* vp1 = vp0 + 8 * 4096;
    const size_t KADV = 64 * 6144;
    const size_t VADV = 128;
    char* ksA = (char*)Ks[0] + w * 2048;
    char* ksB = (char*)Ks[1] + w * 2048;
    char* vsA = (char*)Vs[0] + w * 2048;
    char* vsB = (char*)Vs[1] + w * 2048;

    gload16(kp0, ksA); gload16(kp1, ksA + 1024);
    gload16(vp0, vsA); gload16(vp1, vsA + 1024);
    kp0 += KADV; kp1 += KADV; vp0 += VADV; vp1 += VADV;
    __syncthreads();

    for (int kt = 0; kt < S_ / 64; ++kt) {
        const int cur = kt & 1;
        if (kt < S_ / 64 - 1) {
            char* kd = cur ? ksA : ksB;
            char* vd = cur ? vsA : vsB;
            gload16(kp0, kd); gload16(kp1, kd + 1024);
            gload16(vp0, vd); gload16(vp1, vd + 1024);
            kp0 += KADV; kp1 += KADV; vp0 += VADV; vp1 += VADV;
        }

        // S^T = K @ Q^T : two 32-key halves, K-dim 64 in 4 steps of 16
        const char* Kb_ = (const char*)Ks[cur];
        f32x16 sfr[2];
        __builtin_amdgcn_s_setprio(1);
#pragma unroll
        for (int kh = 0; kh < 2; ++kh) {
            int r = kh * 32 + l31;
            int rsw = (r & 7) << 4;
            const char* Kr = Kb_ + r * 128;
            f32x16 t;
#pragma unroll
            for (int i = 0; i < 16; ++i) t[i] = 0.f;
#pragma unroll
            for (int ds = 0; ds < 4; ++ds) {
                bf16x8 kf = *(const bf16x8*)(Kr + ((((ds * 2 + lh) << 4)) ^ rsw));
                t = __builtin_amdgcn_mfma_f32_32x32x16_bf16(kf, qf[ds], t, 0, 0, 0);
            }
            sfr[kh] = t;
        }
        __builtin_amdgcn_s_setprio(0);
        // sfr[kh][i]: score of key (kh*32 + (i&3)+8*(i>>2)+4*lh) for query l31

        // lane-local 32-max + one cross-half reduce
        float mx = fmaxf(sfr[0][0], sfr[1][0]);
#pragma unroll
        for (int i = 1; i < 16; ++i) mx = fmaxf(mx, fmaxf(sfr[0][i], sfr[1][i]));
        mx = fmaxf(mx, __shfl_xor(mx, 32, 64));

        // defer-max rescale (lane-local: O^T col = this lane's query)
        bool need = mx > mold + THRRAW;
        if (__any(need)) {
            float mnew = fmaxf(mold, mx);
            float al = __builtin_amdgcn_exp2f((mold - mnew) * C2);
            lsum *= al;
            mold = mnew;
#pragma unroll
            for (int i = 0; i < 16; ++i) { oacc[0][i] *= al; oacc[1][i] *= al; }
        }

        // P = exp2(C2*s - C2*m), lane-local sum; P regs ARE the PV B-frags
        float nm = -mold * C2;
        float pv0[16], pv1[16];
        float psum = 0.f;
#pragma unroll
        for (int i = 0; i < 16; ++i) {
            pv0[i] = __builtin_amdgcn_exp2f(fmaf(sfr[0][i], C2, nm));
            pv1[i] = __builtin_amdgcn_exp2f(fmaf(sfr[1][i], C2, nm));
            psum += pv0[i] + pv1[i];
        }
        psum += __shfl_xor(psum, 32, 64);
        lsum += psum;

        bf16x8 pf[4];
#pragma unroll
        for (int j = 0; j < 8; ++j) {
            pf[0][j] = (__bf16)pv0[j];
            pf[1][j] = (__bf16)pv0[8 + j];
            pf[2][j] = (__bf16)pv1[j];
            pf[3][j] = (__bf16)pv1[8 + j];
        }

        // O^T += V^T @ P^T  (A = sigma-permuted Vt rows, B = P^T from registers)
        {
            const char* Vb_ = (const char*)Vs[cur];
            __builtin_amdgcn_s_setprio(1);
#pragma unroll
            for (int dh = 0; dh < 2; ++dh) {
                int r = dh * 32 + l31;
                int rsw = (r & 7) << 4;
                const char* Vr = Vb_ + r * 128;
#pragma unroll
                for (int ks = 0; ks < 4; ++ks) {
                    bf16x8 vf = *(const bf16x8*)(Vr + ((((ks * 2 + lh) << 4)) ^ rsw));
                    oacc[dh] = __builtin_amdgcn_mfma_f32_32x32x16_bf16(vf, pf[ks], oacc[dh], 0, 0, 0);
                }
            }
            __builtin_amdgcn_s_setprio(0);
        }
        __syncthreads();   // drains prefetch vmcnt + protects buffer swap
    }

    // epilogue: O^T col = query (lane-local stats); reg groups of 4 = consecutive d
    float invl = 1.0f / lsum;
    char* Og = (char*)O + ((size_t)(b * S_ + q0 + w * 32 + l31) * 1024 + h * 64) * 2;
#pragma unroll
    for (int dh = 0; dh < 2; ++dh)
#pragma unroll
        for (int t4 = 0; t4 < 4; ++t4) {
            int db = dh * 32 + t4 * 8 + lh * 4;
            bf16x4 ov = {(__bf16)(oacc[dh][t4 * 4] * invl),
                         (__bf16)(oacc[dh][t4 * 4 + 1] * invl),
                         (__bf16)(oacc[dh][t4 * 4 + 2] * invl),
                         (__bf16)(oacc[dh][t4 * 4 + 3] * invl)};
            *(bf16x4*)(Og + db * 2) = ov;
        }
}

// ---------------- launch ----------------
extern "C" void kernel_launch(void* const* d_in, const int* in_sizes, int n_in,
                              void* d_out, int out_size, void* d_ws, size_t ws_size,
                              hipStream_t stream) {
    const float* x     = (const float*)d_in[0];
    const float* Wq    = (const float*)d_in[1];
    const float* bq    = (const float*)d_in[2];
    const float* Wk    = (const float*)d_in[3];
    const float* bk    = (const float*)d_in[4];
    const float* Wv    = (const float*)d_in[5];
    const float* bv    = (const float*)d_in[6];
    const float* Wo    = (const float*)d_in[7];
    const float* bo    = (const float*)d_in[8];
    const float* ln1_g = (const float*)d_in[9];
    const float* ln1_b = (const float*)d_in[10];
    const float* ln2_g = (const float*)d_in[11];
    const float* ln2_b = (const float*)d_in[12];
    const float* W1    = (const float*)d_in[13];
    const float* b1    = (const float*)d_in[14];
    const float* W2    = (const float*)d_in[15];
    const float* b2    = (const float*)d_in[16];
    float* out = (float*)d_out;

    const size_t MB = 1ull << 20;
    char* ws = (char*)d_ws;
    u16* QKVb = (u16*)(ws + 0 * MB);      // 48MB [8192][3072]
    u16* aout = (u16*)(ws + 48 * MB);     // 16MB [8192][1024]
    u16* mid  = (u16*)(ws + 0 * MB);      // 64MB [8192][4096] (reuses QKVb+aout after out-proj)
    float* x2 = (float*)(ws + 64 * MB);   // 32MB f32
    float* bqkv = (float*)(ws + 64 * MB); // 12KB (dead once x2 is written)
    u16* xn   = (u16*)(ws + 96 * MB);     // 16MB
    u16* Vt   = (u16*)(ws + 96 * MB);     // 16MB (reuses xn after QKV)
    u16* xn2  = (u16*)(ws + 96 * MB);     // 16MB (reuses Vt after attn)
    u16* Wqkvt = (u16*)(ws + 112 * MB);   // 6MB [3072][1024]
    u16* Wot  = Wqkvt + (size_t)3072 * D_;// 2MB
    u16* W1t  = (u16*)(ws + 112 * MB);    // 8MB (reuses Wqkvt+Wot after out-proj)
    u16* W2t  = (u16*)(ws + 120 * MB);    // 8MB

    // weight conversions + bias pack
    wtrans_k<<<dim3(32, 32), 256, 0, stream>>>(Wq, Wqkvt, D_, D_);
    wtrans_k<<<dim3(32, 32), 256, 0, stream>>>(Wk, Wqkvt + (size_t)D_ * D_, D_, D_);
    wtrans_k<<<dim3(32, 32), 256, 0, stream>>>(Wv, Wqkvt + (size_t)2 * D_ * D_, D_, D_);
    wtrans_k<<<dim3(32, 32), 256, 0, stream>>>(Wo, Wot, D_, D_);
    wtrans_k<<<dim3(32, 128), 256, 0, stream>>>(W2, W2t, MLP_, D_);
    pack3_k<<<3, 1024, 0, stream>>>(bq, bk, bv, bqkv);

    // LN1
    ln_bf16_k<<<MROWS, 256, 0, stream>>>(x, ln1_g, ln1_b, xn);
    // fused QKV projection: [8192][3072]
    gemm_bf16<0><<<dim3(24, 64), 256, 0, stream>>>(xn, Wqkvt, bqkv, nullptr, QKVb, MROWS, 3072, D_);
    // V transpose per head (sigma-permuted columns)
    vtrans_k<<<dim3(32, 64), 256, 0, stream>>>(QKVb, Vt);
    // attention (128 queries/block)
    attn_mfma<<<dim3(16, 64), 256, 0, stream>>>(QKVb, Vt, aout);
    // out projection + residual -> x2 (f32)
    gemm_bf16<2><<<dim3(8, 64), 256, 0, stream>>>(aout, Wot, bo, x, x2, MROWS, D_, D_);
    // W1 transpose (Wqkvt/Wot now dead), LN2
    wtrans_k<<<dim3(128, 32), 256, 0, stream>>>(W1, W1t, D_, MLP_);
    ln_bf16_k<<<MROWS, 256, 0, stream>>>(x2, ln2_g, ln2_b, xn2);
    // MLP
    gemm_bf16<1><<<dim3(32, 64), 256, 0, stream>>>(xn2, W1t, b1, nullptr, mid, MROWS, MLP_, D_);
    gemm_bf16<2><<<dim3(8, 64), 256, 0, stream>>>(mid, W2t, b2, x2, (void*)out, MROWS, D_, MLP_);
}